// Round 9
// baseline (255.056 us; speedup 1.0000x reference)
//
#include <hip/hip_runtime.h>
#include <hip/hip_bf16.h>
#include <math.h>

#define BATCH 16
#define LSEQ 4096
#define DMODEL 256
#define NST 16
#define LC 64                   // rows per fused block
#define LCH 32                  // scan sub-chunk
#define NCHB (LSEQ / LC)        // 64 blocks per batch
#define NCH_ST (LSEQ / LCH)     // 128 state sub-chunks per batch
#define MROWS (BATCH * LSEQ)    // 65536
#define LOG2E 1.44269504088896340736f
#define LN2 0.6931471805599453f

typedef float f32x4 __attribute__((ext_vector_type(4)));
typedef short bf16x8 __attribute__((ext_vector_type(8)));

__device__ __forceinline__ float silu_fast(float v) {
  return v * __builtin_amdgcn_rcpf(1.f + __builtin_amdgcn_exp2f(-v * LOG2E));
}
__device__ __forceinline__ float softplus_fast(float v) {
  float l = LN2 * __builtin_amdgcn_logf(1.f + __builtin_amdgcn_exp2f(v * LOG2E));
  return v > 16.f ? v : l;
}
__device__ __forceinline__ uint bf16rne(float f) {
  uint u = __float_as_uint(f);
  return (u + 0x7fffu + ((u >> 16) & 1u)) >> 16;
}
__device__ __forceinline__ float bf2f(ushort u) {
  return __uint_as_float((uint)u << 16);
}
__device__ __forceinline__ ushort f2h(float v) {
  _Float16 h = (_Float16)v;
  return __builtin_bit_cast(ushort, h);
}
__device__ __forceinline__ float h2f(ushort u) {
  return (float)__builtin_bit_cast(_Float16, u);
}
__device__ __forceinline__ uint pk2(float x, float y) {
  return bf16rne(x) | (bf16rne(y) << 16);
}
__device__ __forceinline__ uint4 pk8(float4 a, float4 b) {
  uint4 r;
  r.x = pk2(a.x, a.y);
  r.y = pk2(a.z, a.w);
  r.z = pk2(b.x, b.y);
  r.w = pk2(b.z, b.w);
  return r;
}

// p[n] = e1^(n+1), 15 muls, dep depth 4
__device__ __forceinline__ void pow16(float e1, float* p) {
  p[0] = e1;
  p[1] = e1 * e1;
  p[2] = p[1] * e1;
  p[3] = p[1] * p[1];
  p[4] = p[3] * e1;
  p[5] = p[3] * p[1];
  p[6] = p[3] * p[2];
  p[7] = p[3] * p[3];
  p[8] = p[7] * e1;
  p[9] = p[7] * p[1];
  p[10] = p[7] * p[2];
  p[11] = p[7] * p[3];
  p[12] = p[7] * p[4];
  p[13] = p[7] * p[5];
  p[14] = p[7] * p[6];
  p[15] = p[7] * p[7];
}

// async global(bf16)->LDS, 16 B per lane (dest = wave-uniform base + lane*16)
__device__ __forceinline__ void glds16(const ushort* g, char* l) {
  __builtin_amdgcn_global_load_lds(
      (const __attribute__((address_space(1))) void*)g,
      (__attribute__((address_space(3))) void*)l, 16, 0, 0);
}

// stage a 256x32 bf16 B k-slice into dst (layout byte = r*64 + slot*16,
// slot = srcchunk ^ ((r+(r>>2))&3)), 512-thread version: wave w covers
// 1KB blocks w*2 and w*2+1.
__device__ __forceinline__ void stageB512(const ushort* gbase, char* dst,
                                          int k0, int lane, int wid) {
#pragma unroll
  for (int c = 0; c < 2; ++c) {
    int r = (wid * 2 + c) * 16 + (lane >> 2);
    int sA = (r + (r >> 2)) & 3;
    int cA = (lane & 3) ^ sA;
    glds16(gbase + (size_t)r * 256 + cA * 8 + k0, dst + (wid * 2 + c) * 1024);
  }
}

// ---------------------------------------------------------------------------
// Weight fp32->bf16 convert. dst layout (ushort offsets):
//   [0,131072) W_in | [131072,196608) W_delta | [196608,262144) W_out
//   [262144,266240) W_B | [266240,270336) W_C
// ---------------------------------------------------------------------------
__global__ __launch_bounds__(256) void cvt_weights(
    const float* __restrict__ Win, const float* __restrict__ Wd,
    const float* __restrict__ Wo, const float* __restrict__ WB,
    const float* __restrict__ WC, ushort* __restrict__ dst) {
  size_t i = ((size_t)blockIdx.x * 256 + threadIdx.x) * 8;
  if (i >= 270336) return;
  const float* s;
  size_t o;
  if (i < 131072)      { s = Win; o = i; }
  else if (i < 196608) { s = Wd;  o = i - 131072; }
  else if (i < 262144) { s = Wo;  o = i - 196608; }
  else if (i < 266240) { s = WB;  o = i - 262144; }
  else                 { s = WC;  o = i - 266240; }
  float4 a = *(const float4*)(s + o);
  float4 b = *(const float4*)(s + o + 4);
  *(uint4*)(dst + i) = pk8(a, b);
}

// ---------------------------------------------------------------------------
// gemm_in: xz = x @ W_in^T + b_in. Tile 64x256, grid (2, M/64);
// col<256 -> x_in fp32, col>=256 -> silu(z) bf16.  (unchanged structure)
// ---------------------------------------------------------------------------
__global__ __launch_bounds__(256, 4) void gemm_in(
    const float* __restrict__ A, const ushort* __restrict__ Bbf,
    const float* __restrict__ bias, float* __restrict__ out0,
    ushort* __restrict__ out1) {
  constexpr int KD = 256;
  __shared__ char smem[40960];
  const int tid = threadIdx.x;
  const int lane = tid & 63, wid = tid >> 6;
  const int M0 = blockIdx.y * 64;
  const int N0 = blockIdx.x * 256;

  const int rA = tid >> 2, cA = tid & 3;
  const int sA = (rA + (rA >> 2)) & 3;
  const int ldsAoff = rA * 64 + ((cA ^ sA) * 16);
  const float* gA32 = A + (size_t)(M0 + rA) * KD + cA * 8;
  const ushort* gB = Bbf + (size_t)(N0 + rA) * KD + ((cA ^ sA) * 8);

  f32x4 acc[4][4];
#pragma unroll
  for (int i = 0; i < 4; ++i)
#pragma unroll
    for (int j = 0; j < 4; ++j) acc[i][j] = {0.f, 0.f, 0.f, 0.f};

  {
#pragma unroll
    for (int i = 0; i < 4; ++i)
      glds16(gB + (size_t)i * 64 * KD, smem + 4096 + i * 4096 + wid * 1024);
    float4 a0 = *(const float4*)(gA32);
    float4 a1 = *(const float4*)(gA32 + 4);
    *(uint4*)(smem + ldsAoff) = pk8(a0, a1);
  }
  __syncthreads();

  for (int step = 0; step < 8; ++step) {
    const int cur = step & 1;
    char* bufc = smem + cur * 20480;
    char* bufn = smem + (cur ^ 1) * 20480;
    float4 na0, na1;
    if (step < 7) {
      const int k0 = (step + 1) * 32;
#pragma unroll
      for (int i = 0; i < 4; ++i)
        glds16(gB + (size_t)i * 64 * KD + k0,
               bufn + 4096 + i * 4096 + wid * 1024);
      na0 = *(const float4*)(gA32 + k0);
      na1 = *(const float4*)(gA32 + k0 + 4);
    }
    bf16x8 af[4], bfr[4];
#pragma unroll
    for (int i = 0; i < 4; ++i) {
      int r = i * 16 + (lane & 15);
      int slot = (lane >> 4) ^ ((r + (r >> 2)) & 3);
      af[i] = *(const bf16x8*)(bufc + r * 64 + slot * 16);
    }
#pragma unroll
    for (int j = 0; j < 4; ++j) {
      int r = wid * 64 + j * 16 + (lane & 15);
      int slot = (lane >> 4) ^ ((r + (r >> 2)) & 3);
      bfr[j] = *(const bf16x8*)(bufc + 4096 + r * 64 + slot * 16);
    }
#pragma unroll
    for (int i = 0; i < 4; ++i)
#pragma unroll
      for (int j = 0; j < 4; ++j)
        acc[i][j] = __builtin_amdgcn_mfma_f32_16x16x32_bf16(af[i], bfr[j],
                                                            acc[i][j], 0, 0, 0);
    if (step < 7) *(uint4*)(bufn + ldsAoff) = pk8(na0, na1);
    __syncthreads();
  }

  const int rbase = (lane >> 4) * 4;
  const int cn = lane & 15;
#pragma unroll
  for (int i = 0; i < 4; ++i) {
#pragma unroll
    for (int j = 0; j < 4; ++j) {
      int col = N0 + wid * 64 + j * 16 + cn;
      float bs = bias[col];
#pragma unroll
      for (int r = 0; r < 4; ++r) {
        int row = M0 + i * 16 + rbase + r;
        float v = acc[i][j][r] + bs;
        if (col < DMODEL)
          out0[(size_t)row * DMODEL + col] = v;
        else
          out1[(size_t)row * DMODEL + (col - DMODEL)] =
              (ushort)bf16rne(silu_fast(v));
      }
    }
  }
}

// ---------------------------------------------------------------------------
// K2 fused_mid (512 thr, 8 waves): conv+silu -> xc tile, delta GEMM
// (wave tile 64x32), BC GEMM (waves 0-3), scan pass1 over two 32-row
// sub-chunks (thread half = tid>>8).
// LDS: @0 xc bf16 [64][32c] swz c^(r&7)                (32 KB)
//      @32768 B dbuf 16KBx2 -> delta fp16 [64][256] swz (32 KB)
//      @65536 WBC [32][32c] swz -> BC f32 [64][32]      (16 KB)
// ---------------------------------------------------------------------------
__global__ __launch_bounds__(512, 2) void fused_mid(
    const float* __restrict__ xin, const ushort* __restrict__ wdl,
    const ushort* __restrict__ wbc, const float* __restrict__ b_delta,
    const float* __restrict__ A_log, const float* __restrict__ conv_w,
    const float* __restrict__ conv_b, ushort* __restrict__ xc_g,
    ushort* __restrict__ dl_g, ushort* __restrict__ bc_g,
    float* __restrict__ hout, float* __restrict__ cumA) {
  __shared__ char smem[81920];
  const int tid = threadIdx.x, lane = tid & 63, wid = tid >> 6;
  const int b = blockIdx.x / NCHB, c = blockIdx.x % NCHB;
  const int l0 = c * LC;
  const size_t row0 = (size_t)b * LSEQ + l0;

  // ---- WBC staging (32 rows x 256): wave w covers 1KB blocks w*2, w*2+1
  {
#pragma unroll
    for (int cc = 0; cc < 2; ++cc) {
      int row = (wid * 2 + cc) * 2 + (lane >> 5);
      int slot = lane & 31;
      int cB = slot ^ (row & 7);
      glds16(wbc + (size_t)row * 256 + cB * 8,
             smem + 65536 + (wid * 2 + cc) * 1024);
    }
  }
  // ---- W_delta k-step 0
  stageB512(wdl, smem + 32768, 0, lane, wid);

  // ---- conv + silu -> xc tile + global (each thread 4 l-rows x 8 d)
  {
    const int dq = tid & 31;
    const int d0 = dq * 8;
    float w0[8], w1[8], w2[8], cb[8];
#pragma unroll
    for (int k = 0; k < 8; ++k) {
      w0[k] = conv_w[(d0 + k) * 3 + 0];
      w1[k] = conv_w[(d0 + k) * 3 + 1];
      w2[k] = conv_w[(d0 + k) * 3 + 2];
      cb[k] = conv_b[d0 + k];
    }
#pragma unroll
    for (int it = 0; it < 4; ++it) {
      const int lr = it * 16 + (tid >> 5);
      const int l = l0 + lr;
      const size_t bp = (row0 + lr) * DMODEL + d0;
      float4 zf = {0.f, 0.f, 0.f, 0.f};
      float4 m0 = zf, m1 = zf, p0 = zf, p1 = zf;
      if (l > 0) {
        m0 = *(const float4*)(xin + bp - DMODEL);
        m1 = *(const float4*)(xin + bp - DMODEL + 4);
      }
      float4 c0 = *(const float4*)(xin + bp);
      float4 c1 = *(const float4*)(xin + bp + 4);
      if (l < LSEQ - 1) {
        p0 = *(const float4*)(xin + bp + DMODEL);
        p1 = *(const float4*)(xin + bp + DMODEL + 4);
      }
      float mv[8] = {m0.x, m0.y, m0.z, m0.w, m1.x, m1.y, m1.z, m1.w};
      float cv[8] = {c0.x, c0.y, c0.z, c0.w, c1.x, c1.y, c1.z, c1.w};
      float pv[8] = {p0.x, p0.y, p0.z, p0.w, p1.x, p1.y, p1.z, p1.w};
      float ov[8];
#pragma unroll
      for (int k = 0; k < 8; ++k) {
        float o = fmaf(w0[k], mv[k], fmaf(w1[k], cv[k], fmaf(w2[k], pv[k], cb[k])));
        ov[k] = silu_fast(o);
      }
      uint4 r4;
      r4.x = pk2(ov[0], ov[1]);
      r4.y = pk2(ov[2], ov[3]);
      r4.z = pk2(ov[4], ov[5]);
      r4.w = pk2(ov[6], ov[7]);
      *(uint4*)(xc_g + bp) = r4;
      *(uint4*)(smem + lr * 512 + ((dq ^ (lr & 7)) * 16)) = r4;
    }
  }
  __syncthreads();  // xc tile + WBC + B-k0 ready

  // ---- delta GEMM: wave w -> cols w*32..w*32+31; acc 4x2
  f32x4 acc[4][2];
#pragma unroll
  for (int i = 0; i < 4; ++i)
#pragma unroll
    for (int j = 0; j < 2; ++j) acc[i][j] = {0.f, 0.f, 0.f, 0.f};

  for (int step = 0; step < 8; ++step) {
    char* bufc = smem + 32768 + (step & 1) * 16384;
    if (step < 7)
      stageB512(wdl, smem + 32768 + ((step + 1) & 1) * 16384,
                (step + 1) * 32, lane, wid);
    bf16x8 af[4], bfr[2];
#pragma unroll
    for (int i = 0; i < 4; ++i) {
      int r = i * 16 + (lane & 15);
      int sc = step * 4 + (lane >> 4);
      af[i] = *(const bf16x8*)(smem + r * 512 + ((sc ^ (r & 7)) * 16));
    }
#pragma unroll
    for (int j = 0; j < 2; ++j) {
      int r = wid * 32 + j * 16 + (lane & 15);
      int slot = (lane >> 4) ^ ((r + (r >> 2)) & 3);
      bfr[j] = *(const bf16x8*)(bufc + r * 64 + slot * 16);
    }
#pragma unroll
    for (int i = 0; i < 4; ++i)
#pragma unroll
      for (int j = 0; j < 2; ++j)
        acc[i][j] = __builtin_amdgcn_mfma_f32_16x16x32_bf16(af[i], bfr[j],
                                                            acc[i][j], 0, 0, 0);
    __syncthreads();
  }

  // ---- BC GEMM (waves 0-3; wave w -> rows w*16..w*16+15)
  f32x4 accbc[2];
  accbc[0] = {0.f, 0.f, 0.f, 0.f};
  accbc[1] = {0.f, 0.f, 0.f, 0.f};
  if (wid < 4) {
#pragma unroll
    for (int step = 0; step < 8; ++step) {
      int sc = step * 4 + (lane >> 4);
      int ra = wid * 16 + (lane & 15);
      bf16x8 a2 = *(const bf16x8*)(smem + ra * 512 + ((sc ^ (ra & 7)) * 16));
#pragma unroll
      for (int j = 0; j < 2; ++j) {
        int br = j * 16 + (lane & 15);
        bf16x8 b2 =
            *(const bf16x8*)(smem + 65536 + br * 512 + ((sc ^ (br & 7)) * 16));
        accbc[j] =
            __builtin_amdgcn_mfma_f32_16x16x32_bf16(a2, b2, accbc[j], 0, 0, 0);
      }
    }
  }

  // ---- delta epilogue -> dtile fp16 [64][256] swz @32768
  const int rbase = (lane >> 4) * 4;
  const int cn = lane & 15;
#pragma unroll
  for (int i = 0; i < 4; ++i)
#pragma unroll
    for (int j = 0; j < 2; ++j) {
      int col = wid * 32 + j * 16 + cn;
      float bs = b_delta[col];
#pragma unroll
      for (int r = 0; r < 4; ++r) {
        int row = i * 16 + rbase + r;
        *(ushort*)(smem + 32768 + row * 512 +
                   ((col * 2) ^ (((row >> 2) & 3) << 5))) =
            f2h(softplus_fast(acc[i][j][r] + bs));
      }
    }
  __syncthreads();  // all WBC reads + dtile writes done

  // ---- BC epilogue (waves 0-3): BC f32 @65536 + bc_g
  if (wid < 4) {
#pragma unroll
    for (int j = 0; j < 2; ++j)
#pragma unroll
      for (int r = 0; r < 4; ++r) {
        int row = wid * 16 + rbase + r;
        int col = j * 16 + cn;
        ushort bv = (ushort)bf16rne(accbc[j][r]);
        ((float*)(smem + 65536))[row * 32 + col] = bf2f(bv);
        bc_g[(row0 + row) * 32 + col] = bv;
      }
  }
  // ---- dl_g coalesced write from dtile
#pragma unroll
  for (int it = 0; it < 4; ++it) {
    int idx = it * 512 + tid;
    int row = idx >> 5, ch = idx & 31;
    *(uint4*)(dl_g + (row0 + row) * DMODEL + ch * 8) =
        *(const uint4*)(smem + 32768 + row * 512 +
                        ((ch ^ (((row >> 2) & 3) << 1)) * 16));
  }
  __syncthreads();  // BC f32 visible

  // ---- scan pass1: half = tid>>8 scans its own 32-row sub-chunk
  const int half = tid >> 8;
  const int d = tid & 255;
  const int lb0 = half * LCH;
  float Aa2[NST];
#pragma unroll
  for (int q = 0; q < 4; ++q) {
    float4 v = *(const float4*)(A_log + d * NST + q * 4);
    Aa2[q * 4 + 0] = -LOG2E * __expf(v.x);
    Aa2[q * 4 + 1] = -LOG2E * __expf(v.y);
    Aa2[q * 4 + 2] = -LOG2E * __expf(v.z);
    Aa2[q * 4 + 3] = -LOG2E * __expf(v.w);
  }
  bool pm = true;
#pragma unroll
  for (int n = 1; n < NST; ++n)
    pm = pm && (fabsf(Aa2[n] - (float)(n + 1) * Aa2[0]) <=
                1e-3f * fabsf(Aa2[n]));
  float h[NST];
#pragma unroll
  for (int n = 0; n < NST; ++n) h[n] = 0.f;
  float sdt = 0.f;
  const int uoff0 = (d & 7) * 2;
  const int uchunk = d >> 3;
  if (pm) {
#pragma unroll 4
    for (int li = 0; li < LCH; ++li) {
      int l = lb0 + li;
      float dt = h2f(*(const ushort*)(smem + 32768 + l * 512 +
                                      ((d * 2) ^ (((l >> 2) & 3) << 5))));
      float u = bf2f(*(const ushort*)(smem + l * 512 +
                                      ((uchunk ^ (l & 7)) * 16) + uoff0));
      sdt += dt;
      float dtu = dt * u;
      const float* Bp = (const float*)(smem + 65536) + l * 32;
      f32x4 B0 = *(const f32x4*)(Bp);
      f32x4 B1 = *(const f32x4*)(Bp + 4);
      f32x4 B2 = *(const f32x4*)(Bp + 8);
      f32x4 B3 = *(const f32x4*)(Bp + 12);
      float Bv[NST] = {B0.x, B0.y, B0.z, B0.w, B1.x, B1.y, B1.z, B1.w,
                       B2.x, B2.y, B2.z, B2.w, B3.x, B3.y, B3.z, B3.w};
      float p[NST];
      pow16(__builtin_amdgcn_exp2f(dt * Aa2[0]), p);
#pragma unroll
      for (int n = 0; n < NST; ++n) h[n] = fmaf(p[n], h[n], dtu * Bv[n]);
    }
  } else {
#pragma unroll 4
    for (int li = 0; li < LCH; ++li) {
      int l = lb0 + li;
      float dt = h2f(*(const ushort*)(smem + 32768 + l * 512 +
                                      ((d * 2) ^ (((l >> 2) & 3) << 5))));
      float u = bf2f(*(const ushort*)(smem + l * 512 +
                                      ((uchunk ^ (l & 7)) * 16) + uoff0));
      sdt += dt;
      float dtu = dt * u;
      const float* Bp = (const float*)(smem + 65536) + l * 32;
      f32x4 B0 = *(const f32x4*)(Bp);
      f32x4 B1 = *(const f32x4*)(Bp + 4);
      f32x4 B2 = *(const f32x4*)(Bp + 8);
      f32x4 B3 = *(const f32x4*)(Bp + 12);
      float Bv[NST] = {B0.x, B0.y, B0.z, B0.w, B1.x, B1.y, B1.z, B1.w,
                       B2.x, B2.y, B2.z, B2.w, B3.x, B3.y, B3.z, B3.w};
#pragma unroll
      for (int n = 0; n < NST; ++n) {
        float ab = __builtin_amdgcn_exp2f(dt * Aa2[n]);
        h[n] = fmaf(ab, h[n], dtu * Bv[n]);
      }
    }
  }
  float cum[NST];
  if (pm) {
    pow16(__builtin_amdgcn_exp2f(sdt * Aa2[0]), cum);
  } else {
#pragma unroll
    for (int n = 0; n < NST; ++n)
      cum[n] = __builtin_amdgcn_exp2f(sdt * Aa2[n]);
  }
  const size_t ob =
      (((size_t)(b * NCH_ST + c * 2 + half)) * DMODEL + d) * NST;
#pragma unroll
  for (int q = 0; q < 4; ++q) {
    float4 hv = {h[q * 4 + 0], h[q * 4 + 1], h[q * 4 + 2], h[q * 4 + 3]};
    *(float4*)(hout + ob + q * 4) = hv;
    float4 cvv = {cum[q * 4 + 0], cum[q * 4 + 1], cum[q * 4 + 2],
                  cum[q * 4 + 3]};
    *(float4*)(cumA + ob + q * 4) = cvv;
  }
}

// ---------------------------------------------------------------------------
// Scan combine over 128 sub-chunks; in-place h_out -> h_in (fp32).
// ---------------------------------------------------------------------------
__global__ __launch_bounds__(256) void scan_combine(
    float* __restrict__ hstate, const float* __restrict__ cumA) {
  const int t = blockIdx.x * 256 + threadIdx.x;
  const int n = t & (NST - 1);
  const int dd = (t / NST) & (DMODEL - 1);
  const int b = t / (NST * DMODEL);
  float h = 0.f;
  for (int c = 0; c < NCH_ST; ++c) {
    size_t idx = (((size_t)(b * NCH_ST + c)) * DMODEL + dd) * NST + n;
    float ho = hstate[idx];
    float ca = cumA[idx];
    hstate[idx] = h;
    h = fmaf(ca, h, ho);
  }
}

// ---------------------------------------------------------------------------
// K3 fused_out (512 thr): scan pass3 over two 32-row sub-chunks -> y_pre
// LDS tile -> GEMM with W_out -> d_out.
// LDS: @0 ypre bf16 [64][32c] swz (32 KB); @32768 B dbuf 16KBx2;
//      @65536 BC f32 [64][32] (8 KB).
// ---------------------------------------------------------------------------
__global__ __launch_bounds__(512, 2) void fused_out(
    const ushort* __restrict__ dl, const ushort* __restrict__ xcb,
    const ushort* __restrict__ szy, const ushort* __restrict__ bcb,
    const float* __restrict__ A_log, const float* __restrict__ hin,
    const float* __restrict__ Dskip, const ushort* __restrict__ wout,
    const float* __restrict__ b_out, float* __restrict__ out) {
  __shared__ char smem[73728];
  const int tid = threadIdx.x, lane = tid & 63, wid = tid >> 6;
  const int b = blockIdx.x / NCHB, c = blockIdx.x % NCHB;
  const int l0 = c * LC;
  const size_t row0 = (size_t)b * LSEQ + l0;

  // stage BC f32 tile (512 thr x 4 vals)
  {
    int r = tid >> 3, q = tid & 7;
    uint2 v = *(const uint2*)(bcb + (row0 + r) * 32 + q * 4);
    float* dp = (float*)(smem + 65536) + r * 32 + q * 4;
    dp[0] = bf2f((ushort)(v.x & 0xffff));
    dp[1] = bf2f((ushort)(v.x >> 16));
    dp[2] = bf2f((ushort)(v.y & 0xffff));
    dp[3] = bf2f((ushort)(v.y >> 16));
  }
  // issue W_out k-step 0
  stageB512(wout, smem + 32768, 0, lane, wid);

  const int half = tid >> 8;
  const int d = tid & 255;
  const int lb0 = half * LCH;
  float Aa2[NST];
#pragma unroll
  for (int q = 0; q < 4; ++q) {
    float4 v = *(const float4*)(A_log + d * NST + q * 4);
    Aa2[q * 4 + 0] = -LOG2E * __expf(v.x);
    Aa2[q * 4 + 1] = -LOG2E * __expf(v.y);
    Aa2[q * 4 + 2] = -LOG2E * __expf(v.z);
    Aa2[q * 4 + 3] = -LOG2E * __expf(v.w);
  }
  bool pm = true;
#pragma unroll
  for (int n = 1; n < NST; ++n)
    pm = pm && (fabsf(Aa2[n] - (float)(n + 1) * Aa2[0]) <=
                1e-3f * fabsf(Aa2[n]));
  float h[NST];
  const size_t hb =
      (((size_t)(b * NCH_ST + c * 2 + half)) * DMODEL + d) * NST;
#pragma unroll
  for (int q = 0; q < 4; ++q) {
    float4 v = *(const float4*)(hin + hb + q * 4);
    h[q * 4 + 0] = v.x;
    h[q * 4 + 1] = v.y;
    h[q * 4 + 2] = v.z;
    h[q * 4 + 3] = v.w;
  }
  const float dsk = Dskip[d];
  __syncthreads();  // BC tile ready

  // ---- scan own sub-chunk, y_pre -> LDS
  const size_t base = (row0 + lb0) * DMODEL + d;
  const int ywoff = (d & 7) * 2;
  const int ywchunk = d >> 3;
  ushort dtr[4], ur[4], zr[4];
#pragma unroll
  for (int j = 0; j < 4; ++j) {
    dtr[j] = dl[base + (size_t)j * DMODEL];
    ur[j] = xcb[base + (size_t)j * DMODEL];
    zr[j] = szy[base + (size_t)j * DMODEL];
  }
  for (int lb = 0; lb < LCH / 4; ++lb) {
    ushort dtn[4], un[4], zn[4];
    if (lb < LCH / 4 - 1) {
      size_t nb = base + (size_t)(lb * 4 + 4) * DMODEL;
#pragma unroll
      for (int j = 0; j < 4; ++j) {
        dtn[j] = dl[nb + (size_t)j * DMODEL];
        un[j] = xcb[nb + (size_t)j * DMODEL];
        zn[j] = szy[nb + (size_t)j * DMODEL];
      }
    }
#pragma unroll
    for (int j = 0; j < 4; ++j) {
      int l = lb0 + lb * 4 + j;
      float dt = h2f(dtr[j]);
      float u = bf2f(ur[j]);
      float dtu = dt * u;
      const float* Bp = (const float*)(smem + 65536) + l * 32;
      f32x4 B0 = *(const f32x4*)(Bp);
      f32x4 B1 = *(const f32x4*)(Bp + 4);
      f32x4 B2 = *(const f32x4*)(Bp + 8);
      f32x4 B3 = *(const f32x4*)(Bp + 12);
      f32x4 C0 = *(const f32x4*)(Bp + 16);
      f32x4 C1 = *(const f32x4*)(Bp + 20);
      f32x4 C2 = *(const f32x4*)(Bp + 24);
      f32x4 C3 = *(const f32x4*)(Bp + 28);
      float Bv[NST] = {B0.x, B0.y, B0.z, B0.w, B1.x, B1.y, B1.z, B1.w,
                       B2.x, B2.y, B2.z, B2.w, B3.x, B3.y, B3.z, B3.w};
      float Cv[NST] = {C0.x, C0.y, C0.z, C0.w, C1.x, C1.y, C1.z, C1.w,
                       C2.x, C2.y, C2.z, C2.w, C3.x, C3.y, C3.z, C3.w};
      float y = 0.f;
      if (pm) {
        float p[NST];
        pow16(__builtin_amdgcn_exp2f(dt * Aa2[0]), p);
#pragma unroll
        for (int n = 0; n < NST; ++n) {
          h[n] = fmaf(p[n], h[n], dtu * Bv[n]);
          y = fmaf(h[n], Cv[n], y);
        }
      } else {
#pragma unroll
        for (int n = 0; n < NST; ++n) {
          float ab = __builtin_amdgcn_exp2f(dt * Aa2[n]);
          h[n] = fmaf(ab, h[n], dtu * Bv[n]);
          y = fmaf(h[n], Cv[n], y);
        }
      }
      float yp = (y + u * dsk) * bf2f(zr[j]);
      *(ushort*)(smem + l * 512 + ((ywchunk ^ (l & 7)) * 16) + ywoff) =
          (ushort)bf16rne(yp);
    }
#pragma unroll
    for (int j = 0; j < 4; ++j) {
      dtr[j] = dtn[j];
      ur[j] = un[j];
      zr[j] = zn[j];
    }
  }
  __syncthreads();  // ypre tile complete

  // ---- output GEMM: wave w -> cols w*32; acc 4x2
  f32x4 acc[4][2];
#pragma unroll
  for (int i = 0; i < 4; ++i)
#pragma unroll
    for (int j = 0; j < 2; ++j) acc[i][j] = {0.f, 0.f, 0.f, 0.f};

  for (int step = 0; step < 8; ++step) {
    char* bufc = smem + 32768 + (step & 1) * 16384;
    if (step < 7)
      stageB512(wout, smem + 32768 + ((step + 1) & 1) * 16384,
                (step + 1) * 32, lane, wid);
    bf16x8 af[4], bfr[2];
#pragma unroll
    for (int i = 0; i < 4; ++i) {
      int r = i * 16 + (lane & 15);
      int sc = step * 4 + (lane >> 4);
      af[i] = *(const bf16x8*)(smem + r * 512 + ((sc ^ (r & 7)) * 16));
    }
#pragma unroll
    for (int j = 0; j < 2; ++j) {
      int r = wid * 32 + j * 16 + (lane & 15);
      int slot = (lane >> 4) ^ ((r + (r >> 2)) & 3);
      bfr[j] = *(const bf16x8*)(bufc + r * 64 + slot * 16);
    }
#pragma unroll
    for (int i = 0; i < 4; ++i)
#pragma unroll
      for (int j = 0; j < 2; ++j)
        acc[i][j] = __builtin_amdgcn_mfma_f32_16x16x32_bf16(af[i], bfr[j],
                                                            acc[i][j], 0, 0, 0);
    __syncthreads();
  }

  const int rbase = (lane >> 4) * 4;
  const int cn = lane & 15;
#pragma unroll
  for (int i = 0; i < 4; ++i)
#pragma unroll
    for (int j = 0; j < 2; ++j) {
      int col = wid * 32 + j * 16 + cn;
      float bs = b_out[col];
#pragma unroll
      for (int r = 0; r < 4; ++r) {
        int row = i * 16 + rbase + r;
        out[(row0 + row) * DMODEL + col] = acc[i][j][r] + bs;
      }
    }
}

// ---------------------------------------------------------------------------
extern "C" void kernel_launch(void* const* d_in, const int* in_sizes, int n_in,
                              void* d_out, int out_size, void* d_ws,
                              size_t ws_size, hipStream_t stream) {
  const float* x       = (const float*)d_in[0];
  const float* A_log   = (const float*)d_in[1];
  const float* D_skip  = (const float*)d_in[2];
  const float* W_B     = (const float*)d_in[3];
  const float* W_C     = (const float*)d_in[4];
  const float* W_delta = (const float*)d_in[5];
  const float* b_delta = (const float*)d_in[6];
  const float* W_in    = (const float*)d_in[7];
  const float* b_in    = (const float*)d_in[8];
  const float* W_out   = (const float*)d_in[9];
  const float* b_out   = (const float*)d_in[10];
  const float* conv_w  = (const float*)d_in[11];
  const float* conv_b  = (const float*)d_in[12];

  const size_t MD = (size_t)MROWS * DMODEL;                  // 16.78M
  const size_t HP = (size_t)BATCH * NCH_ST * DMODEL * NST;   // 8.39M
  float* xin   = (float*)d_ws;              // x_in fp32 [MD]
  ushort* dl   = (ushort*)(xin + MD);       // delta fp16 [MD]
  ushort* szy  = dl + MD;                   // silu(z) bf16 [MD]
  ushort* xcb  = szy + MD;                  // xc bf16 [MD]
  ushort* bcb  = xcb + MD;                  // bc bf16 [MROWS*32]
  float* hst   = (float*)(bcb + (size_t)MROWS * 32);  // h_out -> h_in [HP]
  float* cumA  = hst + HP;                  // [HP]
  ushort* wbf  = (ushort*)(cumA + HP);      // bf16 weights, 270336

  cvt_weights<<<dim3(132), 256, 0, stream>>>(W_in, W_delta, W_out, W_B, W_C, wbf);
  gemm_in<<<dim3(2, MROWS / 64), 256, 0, stream>>>(x, wbf, b_in, xin, szy);
  fused_mid<<<dim3(BATCH * NCHB), 512, 0, stream>>>(
      xin, wbf + 131072, wbf + 262144, b_delta, A_log, conv_w, conv_b,
      xcb, dl, bcb, hst, cumA);
  scan_combine<<<dim3(BATCH * DMODEL * NST / 256), 256, 0, stream>>>(hst, cumA);
  fused_out<<<dim3(BATCH * NCHB), 512, 0, stream>>>(
      dl, xcb, szy, bcb, A_log, hst, D_skip, wbf + 196608, b_out,
      (float*)d_out);
}

// Round 10
// 205.698 us; speedup vs baseline: 1.2400x; 1.2400x over previous
//
#include <hip/hip_runtime.h>
#include <hip/hip_bf16.h>
#include <math.h>

#define BATCH 16
#define LSEQ 4096
#define DMODEL 256
#define NST 16
#define LC 64                   // rows per fused block / scan chunk
#define NCHB (LSEQ / LC)        // 64 chunks per batch
#define MROWS (BATCH * LSEQ)    // 65536
#define LOG2E 1.44269504088896340736f
#define LN2 0.6931471805599453f

typedef float f32x4 __attribute__((ext_vector_type(4)));
typedef short bf16x8 __attribute__((ext_vector_type(8)));

__device__ __forceinline__ float silu_fast(float v) {
  return v * __builtin_amdgcn_rcpf(1.f + __builtin_amdgcn_exp2f(-v * LOG2E));
}
__device__ __forceinline__ float softplus_fast(float v) {
  float l = LN2 * __builtin_amdgcn_logf(1.f + __builtin_amdgcn_exp2f(v * LOG2E));
  return v > 16.f ? v : l;
}
__device__ __forceinline__ uint bf16rne(float f) {
  uint u = __float_as_uint(f);
  return (u + 0x7fffu + ((u >> 16) & 1u)) >> 16;
}
__device__ __forceinline__ float bf2f(ushort u) {
  return __uint_as_float((uint)u << 16);
}
__device__ __forceinline__ ushort f2h(float v) {
  _Float16 h = (_Float16)v;
  return __builtin_bit_cast(ushort, h);
}
__device__ __forceinline__ float h2f(ushort u) {
  return (float)__builtin_bit_cast(_Float16, u);
}
__device__ __forceinline__ uint pk2(float x, float y) {
  return bf16rne(x) | (bf16rne(y) << 16);
}
__device__ __forceinline__ uint4 pk8(float4 a, float4 b) {
  uint4 r;
  r.x = pk2(a.x, a.y);
  r.y = pk2(a.z, a.w);
  r.z = pk2(b.x, b.y);
  r.w = pk2(b.z, b.w);
  return r;
}

// p[k] = e1^(k+1+8s): powers 1..8 of e1, times e8 when s==1.
// Products identical to full pow16 -> bit-identical results.
__device__ __forceinline__ void pow8half(float e1, int s, float* p) {
  float e2 = e1 * e1, e4 = e2 * e2, e8 = e4 * e4;
  p[0] = e1;
  p[1] = e2;
  p[2] = e2 * e1;
  p[3] = e4;
  p[4] = e4 * e1;
  p[5] = e4 * e2;
  p[6] = e4 * p[2];
  p[7] = e8;
  float sel = s ? e8 : 1.0f;
#pragma unroll
  for (int k = 0; k < 8; ++k) p[k] *= sel;
}

// async global(bf16)->LDS, 16 B per lane (dest = wave-uniform base + lane*16)
__device__ __forceinline__ void glds16(const ushort* g, char* l) {
  __builtin_amdgcn_global_load_lds(
      (const __attribute__((address_space(1))) void*)g,
      (__attribute__((address_space(3))) void*)l, 16, 0, 0);
}

// stage a 256x32 bf16 B k-slice (swizzled layout r*64 + slot*16,
// slot = chunk ^ ((r+(r>>2))&3)); 512 thr: wave w covers 1KB blocks 2w,2w+1.
__device__ __forceinline__ void stageB512(const ushort* gbase, char* dst,
                                          int k0, int lane, int wid) {
#pragma unroll
  for (int c = 0; c < 2; ++c) {
    int r = (wid * 2 + c) * 16 + (lane >> 2);
    int sA = (r + (r >> 2)) & 3;
    int cA = (lane & 3) ^ sA;
    glds16(gbase + (size_t)r * 256 + cA * 8 + k0, dst + (wid * 2 + c) * 1024);
  }
}

// ---------------------------------------------------------------------------
// Weight fp32->bf16 convert. dst layout (ushort offsets):
//   [0,131072) W_in | [131072,196608) W_delta | [196608,262144) W_out
//   [262144,266240) W_B | [266240,270336) W_C
// ---------------------------------------------------------------------------
__global__ __launch_bounds__(256) void cvt_weights(
    const float* __restrict__ Win, const float* __restrict__ Wd,
    const float* __restrict__ Wo, const float* __restrict__ WB,
    const float* __restrict__ WC, ushort* __restrict__ dst) {
  size_t i = ((size_t)blockIdx.x * 256 + threadIdx.x) * 8;
  if (i >= 270336) return;
  const float* s;
  size_t o;
  if (i < 131072)      { s = Win; o = i; }
  else if (i < 196608) { s = Wd;  o = i - 131072; }
  else if (i < 262144) { s = Wo;  o = i - 196608; }
  else if (i < 266240) { s = WB;  o = i - 262144; }
  else                 { s = WC;  o = i - 266240; }
  float4 a = *(const float4*)(s + o);
  float4 b = *(const float4*)(s + o + 4);
  *(uint4*)(dst + i) = pk8(a, b);
}

// ---------------------------------------------------------------------------
// gemm_in: xz = x @ W_in^T + b_in. Tile 64x256, grid (2, M/64);
// col<256 -> x_in fp32, col>=256 -> silu(z) bf16.
// ---------------------------------------------------------------------------
__global__ __launch_bounds__(256, 4) void gemm_in(
    const float* __restrict__ A, const ushort* __restrict__ Bbf,
    const float* __restrict__ bias, float* __restrict__ out0,
    ushort* __restrict__ out1) {
  constexpr int KD = 256;
  __shared__ char smem[40960];
  const int tid = threadIdx.x;
  const int lane = tid & 63, wid = tid >> 6;
  const int M0 = blockIdx.y * 64;
  const int N0 = blockIdx.x * 256;

  const int rA = tid >> 2, cA = tid & 3;
  const int sA = (rA + (rA >> 2)) & 3;
  const int ldsAoff = rA * 64 + ((cA ^ sA) * 16);
  const float* gA32 = A + (size_t)(M0 + rA) * KD + cA * 8;
  const ushort* gB = Bbf + (size_t)(N0 + rA) * KD + ((cA ^ sA) * 8);

  f32x4 acc[4][4];
#pragma unroll
  for (int i = 0; i < 4; ++i)
#pragma unroll
    for (int j = 0; j < 4; ++j) acc[i][j] = {0.f, 0.f, 0.f, 0.f};

  {
#pragma unroll
    for (int i = 0; i < 4; ++i)
      glds16(gB + (size_t)i * 64 * KD, smem + 4096 + i * 4096 + wid * 1024);
    float4 a0 = *(const float4*)(gA32);
    float4 a1 = *(const float4*)(gA32 + 4);
    *(uint4*)(smem + ldsAoff) = pk8(a0, a1);
  }
  __syncthreads();

  for (int step = 0; step < 8; ++step) {
    const int cur = step & 1;
    char* bufc = smem + cur * 20480;
    char* bufn = smem + (cur ^ 1) * 20480;
    float4 na0, na1;
    if (step < 7) {
      const int k0 = (step + 1) * 32;
#pragma unroll
      for (int i = 0; i < 4; ++i)
        glds16(gB + (size_t)i * 64 * KD + k0,
               bufn + 4096 + i * 4096 + wid * 1024);
      na0 = *(const float4*)(gA32 + k0);
      na1 = *(const float4*)(gA32 + k0 + 4);
    }
    bf16x8 af[4], bfr[4];
#pragma unroll
    for (int i = 0; i < 4; ++i) {
      int r = i * 16 + (lane & 15);
      int slot = (lane >> 4) ^ ((r + (r >> 2)) & 3);
      af[i] = *(const bf16x8*)(bufc + r * 64 + slot * 16);
    }
#pragma unroll
    for (int j = 0; j < 4; ++j) {
      int r = wid * 64 + j * 16 + (lane & 15);
      int slot = (lane >> 4) ^ ((r + (r >> 2)) & 3);
      bfr[j] = *(const bf16x8*)(bufc + 4096 + r * 64 + slot * 16);
    }
#pragma unroll
    for (int i = 0; i < 4; ++i)
#pragma unroll
      for (int j = 0; j < 4; ++j)
        acc[i][j] = __builtin_amdgcn_mfma_f32_16x16x32_bf16(af[i], bfr[j],
                                                            acc[i][j], 0, 0, 0);
    if (step < 7) *(uint4*)(bufn + ldsAoff) = pk8(na0, na1);
    __syncthreads();
  }

  const int rbase = (lane >> 4) * 4;
  const int cn = lane & 15;
#pragma unroll
  for (int i = 0; i < 4; ++i) {
#pragma unroll
    for (int j = 0; j < 4; ++j) {
      int col = N0 + wid * 64 + j * 16 + cn;
      float bs = bias[col];
#pragma unroll
      for (int r = 0; r < 4; ++r) {
        int row = M0 + i * 16 + rbase + r;
        float v = acc[i][j][r] + bs;
        if (col < DMODEL)
          out0[(size_t)row * DMODEL + col] = v;
        else
          out1[(size_t)row * DMODEL + (col - DMODEL)] =
              (ushort)bf16rne(silu_fast(v));
      }
    }
  }
}

// ---------------------------------------------------------------------------
// K2 fused_mid (512 thr, 72 KB LDS -> 2 blocks/CU): conv+silu -> xc tile,
// delta GEMM (single-buffered W_delta stream), BC GEMM (interleaved), scan
// pass1 with n-split (2 threads per d, 8 states each).
// LDS: @0 xc bf16 [64][32c] swz                        (32 KB)
//      @32768 B single 16KB -> delta fp16 [64][256] swz (spans to 65536)
//      @49152 WBC [32][32c] swz (16 KB, dies after GEMMs)
//      @65536 BC f32 [64][32]   (8 KB)
// ---------------------------------------------------------------------------
__global__ __launch_bounds__(512, 4) void fused_mid(
    const float* __restrict__ xin, const ushort* __restrict__ wdl,
    const ushort* __restrict__ wbc, const float* __restrict__ b_delta,
    const float* __restrict__ A_log, const float* __restrict__ conv_w,
    const float* __restrict__ conv_b, ushort* __restrict__ xc_g,
    ushort* __restrict__ dl_g, ushort* __restrict__ bc_g,
    float* __restrict__ hout, float* __restrict__ cumA) {
  __shared__ char smem[73728];
  const int tid = threadIdx.x, lane = tid & 63, wid = tid >> 6;
  const int b = blockIdx.x / NCHB, c = blockIdx.x % NCHB;
  const int l0 = c * LC;
  const size_t row0 = (size_t)b * LSEQ + l0;

  // ---- WBC staging (32 rows x 256) -> @49152
  {
#pragma unroll
    for (int cc = 0; cc < 2; ++cc) {
      int row = (wid * 2 + cc) * 2 + (lane >> 5);
      int cB = (lane & 31) ^ (row & 7);
      glds16(wbc + (size_t)row * 256 + cB * 8,
             smem + 49152 + (wid * 2 + cc) * 1024);
    }
  }
  // ---- W_delta k-step 0 -> @32768 (single buffer)
  stageB512(wdl, smem + 32768, 0, lane, wid);

  // ---- conv + silu -> xc tile + global (each thread 4 l-rows x 8 d)
  {
    const int dq = tid & 31;
    const int d0 = dq * 8;
    float w0[8], w1[8], w2[8], cb[8];
#pragma unroll
    for (int k = 0; k < 8; ++k) {
      w0[k] = conv_w[(d0 + k) * 3 + 0];
      w1[k] = conv_w[(d0 + k) * 3 + 1];
      w2[k] = conv_w[(d0 + k) * 3 + 2];
      cb[k] = conv_b[d0 + k];
    }
#pragma unroll
    for (int it = 0; it < 4; ++it) {
      const int lr = it * 16 + (tid >> 5);
      const int l = l0 + lr;
      const size_t bp = (row0 + lr) * DMODEL + d0;
      float4 zf = {0.f, 0.f, 0.f, 0.f};
      float4 m0 = zf, m1 = zf, p0 = zf, p1 = zf;
      if (l > 0) {
        m0 = *(const float4*)(xin + bp - DMODEL);
        m1 = *(const float4*)(xin + bp - DMODEL + 4);
      }
      float4 c0 = *(const float4*)(xin + bp);
      float4 c1 = *(const float4*)(xin + bp + 4);
      if (l < LSEQ - 1) {
        p0 = *(const float4*)(xin + bp + DMODEL);
        p1 = *(const float4*)(xin + bp + DMODEL + 4);
      }
      float mv[8] = {m0.x, m0.y, m0.z, m0.w, m1.x, m1.y, m1.z, m1.w};
      float cv[8] = {c0.x, c0.y, c0.z, c0.w, c1.x, c1.y, c1.z, c1.w};
      float pv[8] = {p0.x, p0.y, p0.z, p0.w, p1.x, p1.y, p1.z, p1.w};
      float ov[8];
#pragma unroll
      for (int k = 0; k < 8; ++k) {
        float o = fmaf(w0[k], mv[k], fmaf(w1[k], cv[k], fmaf(w2[k], pv[k], cb[k])));
        ov[k] = silu_fast(o);
      }
      uint4 r4;
      r4.x = pk2(ov[0], ov[1]);
      r4.y = pk2(ov[2], ov[3]);
      r4.z = pk2(ov[4], ov[5]);
      r4.w = pk2(ov[6], ov[7]);
      *(uint4*)(xc_g + bp) = r4;
      *(uint4*)(smem + lr * 512 + ((dq ^ (lr & 7)) * 16)) = r4;
    }
  }
  __syncthreads();  // xc tile + WBC + B-k0 ready

  // ---- delta GEMM (single-buf B) with BC GEMM interleaved
  f32x4 acc[4][2];
#pragma unroll
  for (int i = 0; i < 4; ++i)
#pragma unroll
    for (int j = 0; j < 2; ++j) acc[i][j] = {0.f, 0.f, 0.f, 0.f};
  f32x4 accbc = {0.f, 0.f, 0.f, 0.f};

  for (int step = 0; step < 8; ++step) {
    bf16x8 af[4], bfr[2];
#pragma unroll
    for (int i = 0; i < 4; ++i) {
      int r = i * 16 + (lane & 15);
      int sc = step * 4 + (lane >> 4);
      af[i] = *(const bf16x8*)(smem + r * 512 + ((sc ^ (r & 7)) * 16));
    }
#pragma unroll
    for (int j = 0; j < 2; ++j) {
      int r = wid * 32 + j * 16 + (lane & 15);
      int slot = (lane >> 4) ^ ((r + (r >> 2)) & 3);
      bfr[j] = *(const bf16x8*)(smem + 32768 + r * 64 + slot * 16);
    }
#pragma unroll
    for (int i = 0; i < 4; ++i)
#pragma unroll
      for (int j = 0; j < 2; ++j)
        acc[i][j] = __builtin_amdgcn_mfma_f32_16x16x32_bf16(af[i], bfr[j],
                                                            acc[i][j], 0, 0, 0);
    __syncthreads();  // all reads of B buffer done
    if (step < 7) stageB512(wdl, smem + 32768, (step + 1) * 32, lane, wid);
    {  // BC GEMM step (all 8 waves; wave w -> rows (w>>1)*16, col blk w&1)
      int sc = step * 4 + (lane >> 4);
      int ra = (wid >> 1) * 16 + (lane & 15);
      bf16x8 a2 = *(const bf16x8*)(smem + ra * 512 + ((sc ^ (ra & 7)) * 16));
      int br = (wid & 1) * 16 + (lane & 15);
      bf16x8 b2 =
          *(const bf16x8*)(smem + 49152 + br * 512 + ((sc ^ (br & 7)) * 16));
      accbc = __builtin_amdgcn_mfma_f32_16x16x32_bf16(a2, b2, accbc, 0, 0, 0);
    }
    __syncthreads();  // staged B visible
  }

  // ---- delta epilogue -> fp16 tile @32768 (over B + WBC), swz
  const int rbase = (lane >> 4) * 4;
  const int cn = lane & 15;
#pragma unroll
  for (int i = 0; i < 4; ++i)
#pragma unroll
    for (int j = 0; j < 2; ++j) {
      int col = wid * 32 + j * 16 + cn;
      float bs = b_delta[col];
#pragma unroll
      for (int r = 0; r < 4; ++r) {
        int row = i * 16 + rbase + r;
        *(ushort*)(smem + 32768 + row * 512 +
                   ((col * 2) ^ (((row >> 2) & 3) << 5))) =
            f2h(softplus_fast(acc[i][j][r] + bs));
      }
    }
  // ---- BC epilogue: BC f32 @65536 + bc_g
  {
#pragma unroll
    for (int r = 0; r < 4; ++r) {
      int row = (wid >> 1) * 16 + rbase + r;
      int col = (wid & 1) * 16 + cn;
      ushort bv = (ushort)bf16rne(accbc[r]);
      ((float*)(smem + 65536))[row * 32 + col] = bf2f(bv);
      bc_g[(row0 + row) * 32 + col] = bv;
    }
  }
  __syncthreads();  // delta tile + BC f32 visible

  // ---- dl_g coalesced write from delta tile
#pragma unroll
  for (int it = 0; it < 4; ++it) {
    int idx = it * 512 + tid;
    int row = idx >> 5, ch = idx & 31;
    *(uint4*)(dl_g + (row0 + row) * DMODEL + ch * 8) =
        *(const uint4*)(smem + 32768 + row * 512 +
                        ((ch ^ (((row >> 2) & 3) << 1)) * 16));
  }

  // ---- scan pass1, n-split: d = tid>>1, s = tid&1, states [8s, 8s+8)
  const int d = tid >> 1;
  const int s = tid & 1;
  float Aa2h[8];
  {
    float4 v0 = *(const float4*)(A_log + d * NST + 8 * s);
    float4 v1 = *(const float4*)(A_log + d * NST + 8 * s + 4);
    Aa2h[0] = -LOG2E * __expf(v0.x);
    Aa2h[1] = -LOG2E * __expf(v0.y);
    Aa2h[2] = -LOG2E * __expf(v0.z);
    Aa2h[3] = -LOG2E * __expf(v0.w);
    Aa2h[4] = -LOG2E * __expf(v1.x);
    Aa2h[5] = -LOG2E * __expf(v1.y);
    Aa2h[6] = -LOG2E * __expf(v1.z);
    Aa2h[7] = -LOG2E * __expf(v1.w);
  }
  const float Aa2_0 = -LOG2E * __expf(A_log[d * NST]);
  bool pm = true;
#pragma unroll
  for (int k = 0; k < 8; ++k)
    pm = pm && (fabsf(Aa2h[k] - (float)(8 * s + k + 1) * Aa2_0) <=
                1e-3f * fabsf(Aa2h[k]));

  float h[8];
#pragma unroll
  for (int k = 0; k < 8; ++k) h[k] = 0.f;
  float sdt = 0.f;
  const int uoff0 = (d & 7) * 2;
  const int uchunk = d >> 3;
  if (pm) {
#pragma unroll 4
    for (int l = 0; l < LC; ++l) {
      float dt = h2f(*(const ushort*)(smem + 32768 + l * 512 +
                                      ((d * 2) ^ (((l >> 2) & 3) << 5))));
      float u = bf2f(*(const ushort*)(smem + l * 512 +
                                      ((uchunk ^ (l & 7)) * 16) + uoff0));
      sdt += dt;
      float dtu = dt * u;
      const float* Bp = (const float*)(smem + 65536) + l * 32 + 8 * s;
      f32x4 B0 = *(const f32x4*)(Bp);
      f32x4 B1 = *(const f32x4*)(Bp + 4);
      float Bv[8] = {B0.x, B0.y, B0.z, B0.w, B1.x, B1.y, B1.z, B1.w};
      float p[8];
      pow8half(__builtin_amdgcn_exp2f(dt * Aa2_0), s, p);
#pragma unroll
      for (int k = 0; k < 8; ++k) h[k] = fmaf(p[k], h[k], dtu * Bv[k]);
    }
  } else {
#pragma unroll 4
    for (int l = 0; l < LC; ++l) {
      float dt = h2f(*(const ushort*)(smem + 32768 + l * 512 +
                                      ((d * 2) ^ (((l >> 2) & 3) << 5))));
      float u = bf2f(*(const ushort*)(smem + l * 512 +
                                      ((uchunk ^ (l & 7)) * 16) + uoff0));
      sdt += dt;
      float dtu = dt * u;
      const float* Bp = (const float*)(smem + 65536) + l * 32 + 8 * s;
      f32x4 B0 = *(const f32x4*)(Bp);
      f32x4 B1 = *(const f32x4*)(Bp + 4);
      float Bv[8] = {B0.x, B0.y, B0.z, B0.w, B1.x, B1.y, B1.z, B1.w};
#pragma unroll
      for (int k = 0; k < 8; ++k) {
        float ab = __builtin_amdgcn_exp2f(dt * Aa2h[k]);
        h[k] = fmaf(ab, h[k], dtu * Bv[k]);
      }
    }
  }
  float cum[8];
  if (pm) {
    pow8half(__builtin_amdgcn_exp2f(sdt * Aa2_0), s, cum);
  } else {
#pragma unroll
    for (int k = 0; k < 8; ++k)
      cum[k] = __builtin_amdgcn_exp2f(sdt * Aa2h[k]);
  }
  const size_t ob =
      (((size_t)(b * NCHB + c)) * DMODEL + d) * NST + 8 * s;
#pragma unroll
  for (int q = 0; q < 2; ++q) {
    float4 hv = {h[q * 4 + 0], h[q * 4 + 1], h[q * 4 + 2], h[q * 4 + 3]};
    *(float4*)(hout + ob + q * 4) = hv;
    float4 cvv = {cum[q * 4 + 0], cum[q * 4 + 1], cum[q * 4 + 2],
                  cum[q * 4 + 3]};
    *(float4*)(cumA + ob + q * 4) = cvv;
  }
}

// ---------------------------------------------------------------------------
// Scan combine over 64 chunks; in-place h_out -> h_in (fp32).
// ---------------------------------------------------------------------------
__global__ __launch_bounds__(256) void scan_combine(
    float* __restrict__ hstate, const float* __restrict__ cumA) {
  const int t = blockIdx.x * 256 + threadIdx.x;
  const int n = t & (NST - 1);
  const int dd = (t / NST) & (DMODEL - 1);
  const int b = t / (NST * DMODEL);
  float h = 0.f;
  for (int c = 0; c < NCHB; ++c) {
    size_t idx = (((size_t)(b * NCHB + c)) * DMODEL + dd) * NST + n;
    float ho = hstate[idx];
    float ca = cumA[idx];
    hstate[idx] = h;
    h = fmaf(ca, h, ho);
  }
}

// ---------------------------------------------------------------------------
// K3 fused_out (512 thr, 72 KB LDS): scan pass3 (n-split, shfl_xor y-combine)
// -> y_pre LDS tile -> GEMM with W_out (dbuf) -> d_out.
// LDS: @0 ypre bf16 [64][32c] swz (32 KB); @32768 B dbuf 16KBx2;
//      @65536 BC f32 [64][32] (8 KB).
// ---------------------------------------------------------------------------
__global__ __launch_bounds__(512, 4) void fused_out(
    const ushort* __restrict__ dl, const ushort* __restrict__ xcb,
    const ushort* __restrict__ szy, const ushort* __restrict__ bcb,
    const float* __restrict__ A_log, const float* __restrict__ hin,
    const float* __restrict__ Dskip, const ushort* __restrict__ wout,
    const float* __restrict__ b_out, float* __restrict__ out) {
  __shared__ char smem[73728];
  const int tid = threadIdx.x, lane = tid & 63, wid = tid >> 6;
  const int b = blockIdx.x / NCHB, c = blockIdx.x % NCHB;
  const int l0 = c * LC;
  const size_t row0 = (size_t)b * LSEQ + l0;

  // stage BC f32 tile (512 thr x 4 vals)
  {
    int r = tid >> 3, q = tid & 7;
    uint2 v = *(const uint2*)(bcb + (row0 + r) * 32 + q * 4);
    float* dp = (float*)(smem + 65536) + r * 32 + q * 4;
    dp[0] = bf2f((ushort)(v.x & 0xffff));
    dp[1] = bf2f((ushort)(v.x >> 16));
    dp[2] = bf2f((ushort)(v.y & 0xffff));
    dp[3] = bf2f((ushort)(v.y >> 16));
  }
  // issue W_out k-step 0
  stageB512(wout, smem + 32768, 0, lane, wid);

  // ---- scan setup (n-split)
  const int d = tid >> 1;
  const int s = tid & 1;
  float Aa2h[8];
  {
    float4 v0 = *(const float4*)(A_log + d * NST + 8 * s);
    float4 v1 = *(const float4*)(A_log + d * NST + 8 * s + 4);
    Aa2h[0] = -LOG2E * __expf(v0.x);
    Aa2h[1] = -LOG2E * __expf(v0.y);
    Aa2h[2] = -LOG2E * __expf(v0.z);
    Aa2h[3] = -LOG2E * __expf(v0.w);
    Aa2h[4] = -LOG2E * __expf(v1.x);
    Aa2h[5] = -LOG2E * __expf(v1.y);
    Aa2h[6] = -LOG2E * __expf(v1.z);
    Aa2h[7] = -LOG2E * __expf(v1.w);
  }
  const float Aa2_0 = -LOG2E * __expf(A_log[d * NST]);
  bool pm = true;
#pragma unroll
  for (int k = 0; k < 8; ++k)
    pm = pm && (fabsf(Aa2h[k] - (float)(8 * s + k + 1) * Aa2_0) <=
                1e-3f * fabsf(Aa2h[k]));
  float h[8];
  const size_t hb =
      (((size_t)(b * NCHB + c)) * DMODEL + d) * NST + 8 * s;
  {
    float4 v0 = *(const float4*)(hin + hb);
    float4 v1 = *(const float4*)(hin + hb + 4);
    h[0] = v0.x; h[1] = v0.y; h[2] = v0.z; h[3] = v0.w;
    h[4] = v1.x; h[5] = v1.y; h[6] = v1.z; h[7] = v1.w;
  }
  const float dsk = Dskip[d];
  __syncthreads();  // BC tile ready

  // ---- scan, y_pre -> LDS (both pair lanes write same value)
  const size_t base = row0 * DMODEL + d;
  const int ywoff = (d & 7) * 2;
  const int ywchunk = d >> 3;
  ushort dtr[4], ur[4], zr[4];
#pragma unroll
  for (int j = 0; j < 4; ++j) {
    dtr[j] = dl[base + (size_t)j * DMODEL];
    ur[j] = xcb[base + (size_t)j * DMODEL];
    zr[j] = szy[base + (size_t)j * DMODEL];
  }
  for (int lb = 0; lb < LC / 4; ++lb) {
    ushort dtn[4], un[4], zn[4];
    if (lb < LC / 4 - 1) {
      size_t nb = base + (size_t)(lb * 4 + 4) * DMODEL;
#pragma unroll
      for (int j = 0; j < 4; ++j) {
        dtn[j] = dl[nb + (size_t)j * DMODEL];
        un[j] = xcb[nb + (size_t)j * DMODEL];
        zn[j] = szy[nb + (size_t)j * DMODEL];
      }
    }
#pragma unroll
    for (int j = 0; j < 4; ++j) {
      int l = lb * 4 + j;
      float dt = h2f(dtr[j]);
      float u = bf2f(ur[j]);
      float dtu = dt * u;
      const float* Bp = (const float*)(smem + 65536) + l * 32 + 8 * s;
      f32x4 B0 = *(const f32x4*)(Bp);
      f32x4 B1 = *(const f32x4*)(Bp + 4);
      f32x4 C0 = *(const f32x4*)(Bp + 16);
      f32x4 C1 = *(const f32x4*)(Bp + 20);
      float Bv[8] = {B0.x, B0.y, B0.z, B0.w, B1.x, B1.y, B1.z, B1.w};
      float Cv[8] = {C0.x, C0.y, C0.z, C0.w, C1.x, C1.y, C1.z, C1.w};
      float y = 0.f;
      if (pm) {
        float p[8];
        pow8half(__builtin_amdgcn_exp2f(dt * Aa2_0), s, p);
#pragma unroll
        for (int k = 0; k < 8; ++k) {
          h[k] = fmaf(p[k], h[k], dtu * Bv[k]);
          y = fmaf(h[k], Cv[k], y);
        }
      } else {
#pragma unroll
        for (int k = 0; k < 8; ++k) {
          float ab = __builtin_amdgcn_exp2f(dt * Aa2h[k]);
          h[k] = fmaf(ab, h[k], dtu * Bv[k]);
          y = fmaf(h[k], Cv[k], y);
        }
      }
      y += __shfl_xor(y, 1);  // combine the two n-halves (adjacent lanes)
      float yp = (y + u * dsk) * bf2f(zr[j]);
      *(ushort*)(smem + l * 512 + ((ywchunk ^ (l & 7)) * 16) + ywoff) =
          (ushort)bf16rne(yp);
    }
#pragma unroll
    for (int j = 0; j < 4; ++j) {
      dtr[j] = dtn[j];
      ur[j] = un[j];
      zr[j] = zn[j];
    }
  }
  __syncthreads();  // ypre tile complete

  // ---- output GEMM: wave w -> cols w*32; acc 4x2; dbuf B
  f32x4 acc[4][2];
#pragma unroll
  for (int i = 0; i < 4; ++i)
#pragma unroll
    for (int j = 0; j < 2; ++j) acc[i][j] = {0.f, 0.f, 0.f, 0.f};

  for (int step = 0; step < 8; ++step) {
    char* bufc = smem + 32768 + (step & 1) * 16384;
    if (step < 7)
      stageB512(wout, smem + 32768 + ((step + 1) & 1) * 16384,
                (step + 1) * 32, lane, wid);
    bf16x8 af[4], bfr[2];
#pragma unroll
    for (int i = 0; i < 4; ++i) {
      int r = i * 16 + (lane & 15);
      int sc = step * 4 + (lane >> 4);
      af[i] = *(const bf16x8*)(smem + r * 512 + ((sc ^ (r & 7)) * 16));
    }
#pragma unroll
    for (int j = 0; j < 2; ++j) {
      int r = wid * 32 + j * 16 + (lane & 15);
      int slot = (lane >> 4) ^ ((r + (r >> 2)) & 3);
      bfr[j] = *(const bf16x8*)(bufc + r * 64 + slot * 16);
    }
#pragma unroll
    for (int i = 0; i < 4; ++i)
#pragma unroll
      for (int j = 0; j < 2; ++j)
        acc[i][j] = __builtin_amdgcn_mfma_f32_16x16x32_bf16(af[i], bfr[j],
                                                            acc[i][j], 0, 0, 0);
    __syncthreads();
  }

  const int rbase = (lane >> 4) * 4;
  const int cn = lane & 15;
#pragma unroll
  for (int i = 0; i < 4; ++i)
#pragma unroll
    for (int j = 0; j < 2; ++j) {
      int col = wid * 32 + j * 16 + cn;
      float bs = b_out[col];
#pragma unroll
      for (int r = 0; r < 4; ++r) {
        int row = i * 16 + rbase + r;
        out[(row0 + row) * DMODEL + col] = acc[i][j][r] + bs;
      }
    }
}

// ---------------------------------------------------------------------------
extern "C" void kernel_launch(void* const* d_in, const int* in_sizes, int n_in,
                              void* d_out, int out_size, void* d_ws,
                              size_t ws_size, hipStream_t stream) {
  const float* x       = (const float*)d_in[0];
  const float* A_log   = (const float*)d_in[1];
  const float* D_skip  = (const float*)d_in[2];
  const float* W_B     = (const float*)d_in[3];
  const float* W_C     = (const float*)d_in[4];
  const float* W_delta = (const float*)d_in[5];
  const float* b_delta = (const float*)d_in[6];
  const float* W_in    = (const float*)d_in[7];
  const float* b_in    = (const float*)d_in[8];
  const float* W_out   = (const float*)d_in[9];
  const float* b_out   = (const float*)d_in[10];
  const float* conv_w  = (const float*)d_in[11];
  const float* conv_b  = (const float*)d_in[12];

  const size_t MD = (size_t)MROWS * DMODEL;                // 16.78M
  const size_t HP = (size_t)BATCH * NCHB * DMODEL * NST;   // 4.19M
  float* xin   = (float*)d_ws;              // x_in fp32 [MD]
  ushort* dl   = (ushort*)(xin + MD);       // delta fp16 [MD]
  ushort* szy  = dl + MD;                   // silu(z) bf16 [MD]
  ushort* xcb  = szy + MD;                  // xc bf16 [MD]
  ushort* bcb  = xcb + MD;                  // bc bf16 [MROWS*32]
  float* hst   = (float*)(bcb + (size_t)MROWS * 32);  // h_out -> h_in [HP]
  float* cumA  = hst + HP;                  // [HP]
  ushort* wbf  = (ushort*)(cumA + HP);      // bf16 weights, 270336

  cvt_weights<<<dim3(132), 256, 0, stream>>>(W_in, W_delta, W_out, W_B, W_C, wbf);
  gemm_in<<<dim3(2, MROWS / 64), 256, 0, stream>>>(x, wbf, b_in, xin, szy);
  fused_mid<<<dim3(BATCH * NCHB), 512, 0, stream>>>(
      xin, wbf + 131072, wbf + 262144, b_delta, A_log, conv_w, conv_b,
      xcb, dl, bcb, hst, cumA);
  scan_combine<<<dim3(BATCH * DMODEL * NST / 256), 256, 0, stream>>>(hst, cumA);
  fused_out<<<dim3(BATCH * NCHB), 512, 0, stream>>>(
      dl, xcb, szy, bcb, A_log, hst, D_skip, wbf + 196608, b_out,
      (float*)d_out);
}

// Round 11
// 204.705 us; speedup vs baseline: 1.2460x; 1.0049x over previous
//
#include <hip/hip_runtime.h>
#include <hip/hip_bf16.h>
#include <math.h>

#define BATCH 16
#define LSEQ 4096
#define DMODEL 256
#define NST 16
#define LC 64                   // rows per fused block / scan chunk
#define NCHB (LSEQ / LC)        // 64 chunks per batch
#define MROWS (BATCH * LSEQ)    // 65536
#define LOG2E 1.44269504088896340736f
#define LN2 0.6931471805599453f

typedef float f32x4 __attribute__((ext_vector_type(4)));
typedef short bf16x8 __attribute__((ext_vector_type(8)));

__device__ __forceinline__ float silu_fast(float v) {
  return v * __builtin_amdgcn_rcpf(1.f + __builtin_amdgcn_exp2f(-v * LOG2E));
}
__device__ __forceinline__ float softplus_fast(float v) {
  float l = LN2 * __builtin_amdgcn_logf(1.f + __builtin_amdgcn_exp2f(v * LOG2E));
  return v > 16.f ? v : l;
}
__device__ __forceinline__ uint bf16rne(float f) {
  uint u = __float_as_uint(f);
  return (u + 0x7fffu + ((u >> 16) & 1u)) >> 16;
}
__device__ __forceinline__ float bf2f(ushort u) {
  return __uint_as_float((uint)u << 16);
}
__device__ __forceinline__ ushort f2h(float v) {
  _Float16 h = (_Float16)v;
  return __builtin_bit_cast(ushort, h);
}
__device__ __forceinline__ float h2f(ushort u) {
  return (float)__builtin_bit_cast(_Float16, u);
}
__device__ __forceinline__ uint pk2(float x, float y) {
  return bf16rne(x) | (bf16rne(y) << 16);
}
__device__ __forceinline__ uint4 pk8(float4 a, float4 b) {
  uint4 r;
  r.x = pk2(a.x, a.y);
  r.y = pk2(a.z, a.w);
  r.z = pk2(b.x, b.y);
  r.w = pk2(b.z, b.w);
  return r;
}

// p[k] = e1^(k+1+8s): powers 1..8 of e1, times e8 when s==1.
// Products identical to full pow16 -> bit-identical results.
__device__ __forceinline__ void pow8half(float e1, int s, float* p) {
  float e2 = e1 * e1, e4 = e2 * e2, e8 = e4 * e4;
  p[0] = e1;
  p[1] = e2;
  p[2] = e2 * e1;
  p[3] = e4;
  p[4] = e4 * e1;
  p[5] = e4 * e2;
  p[6] = e4 * p[2];
  p[7] = e8;
  float sel = s ? e8 : 1.0f;
#pragma unroll
  for (int k = 0; k < 8; ++k) p[k] *= sel;
}

// async global(bf16)->LDS, 16 B per lane (dest = wave-uniform base + lane*16)
__device__ __forceinline__ void glds16(const ushort* g, char* l) {
  __builtin_amdgcn_global_load_lds(
      (const __attribute__((address_space(1))) void*)g,
      (__attribute__((address_space(3))) void*)l, 16, 0, 0);
}

// stage a 256x32 bf16 B k-slice (swizzled layout r*64 + slot*16,
// slot = chunk ^ ((r+(r>>2))&3)); 512 thr: wave w covers 1KB blocks 2w,2w+1.
__device__ __forceinline__ void stageB512(const ushort* gbase, char* dst,
                                          int k0, int lane, int wid) {
#pragma unroll
  for (int c = 0; c < 2; ++c) {
    int r = (wid * 2 + c) * 16 + (lane >> 2);
    int sA = (r + (r >> 2)) & 3;
    int cA = (lane & 3) ^ sA;
    glds16(gbase + (size_t)r * 256 + cA * 8 + k0, dst + (wid * 2 + c) * 1024);
  }
}

// ---------------------------------------------------------------------------
// Weight fp32->bf16 convert. dst layout (ushort offsets):
//   [0,131072) W_in | [131072,196608) W_delta | [196608,262144) W_out
//   [262144,266240) W_B | [266240,270336) W_C
// ---------------------------------------------------------------------------
__global__ __launch_bounds__(256) void cvt_weights(
    const float* __restrict__ Win, const float* __restrict__ Wd,
    const float* __restrict__ Wo, const float* __restrict__ WB,
    const float* __restrict__ WC, ushort* __restrict__ dst) {
  size_t i = ((size_t)blockIdx.x * 256 + threadIdx.x) * 8;
  if (i >= 270336) return;
  const float* s;
  size_t o;
  if (i < 131072)      { s = Win; o = i; }
  else if (i < 196608) { s = Wd;  o = i - 131072; }
  else if (i < 262144) { s = Wo;  o = i - 196608; }
  else if (i < 266240) { s = WB;  o = i - 262144; }
  else                 { s = WC;  o = i - 266240; }
  float4 a = *(const float4*)(s + o);
  float4 b = *(const float4*)(s + o + 4);
  *(uint4*)(dst + i) = pk8(a, b);
}

// ---------------------------------------------------------------------------
// gemm_in: xz = x @ W_in^T + b_in. Tile 64x256, grid (2, M/64);
// col<256 -> x_in fp32, col>=256 -> silu(z) bf16.
// ---------------------------------------------------------------------------
__global__ __launch_bounds__(256, 4) void gemm_in(
    const float* __restrict__ A, const ushort* __restrict__ Bbf,
    const float* __restrict__ bias, float* __restrict__ out0,
    ushort* __restrict__ out1) {
  constexpr int KD = 256;
  __shared__ char smem[40960];
  const int tid = threadIdx.x;
  const int lane = tid & 63, wid = tid >> 6;
  const int M0 = blockIdx.y * 64;
  const int N0 = blockIdx.x * 256;

  const int rA = tid >> 2, cA = tid & 3;
  const int sA = (rA + (rA >> 2)) & 3;
  const int ldsAoff = rA * 64 + ((cA ^ sA) * 16);
  const float* gA32 = A + (size_t)(M0 + rA) * KD + cA * 8;
  const ushort* gB = Bbf + (size_t)(N0 + rA) * KD + ((cA ^ sA) * 8);

  f32x4 acc[4][4];
#pragma unroll
  for (int i = 0; i < 4; ++i)
#pragma unroll
    for (int j = 0; j < 4; ++j) acc[i][j] = {0.f, 0.f, 0.f, 0.f};

  {
#pragma unroll
    for (int i = 0; i < 4; ++i)
      glds16(gB + (size_t)i * 64 * KD, smem + 4096 + i * 4096 + wid * 1024);
    float4 a0 = *(const float4*)(gA32);
    float4 a1 = *(const float4*)(gA32 + 4);
    *(uint4*)(smem + ldsAoff) = pk8(a0, a1);
  }
  __syncthreads();

  for (int step = 0; step < 8; ++step) {
    const int cur = step & 1;
    char* bufc = smem + cur * 20480;
    char* bufn = smem + (cur ^ 1) * 20480;
    float4 na0, na1;
    if (step < 7) {
      const int k0 = (step + 1) * 32;
#pragma unroll
      for (int i = 0; i < 4; ++i)
        glds16(gB + (size_t)i * 64 * KD + k0,
               bufn + 4096 + i * 4096 + wid * 1024);
      na0 = *(const float4*)(gA32 + k0);
      na1 = *(const float4*)(gA32 + k0 + 4);
    }
    bf16x8 af[4], bfr[4];
#pragma unroll
    for (int i = 0; i < 4; ++i) {
      int r = i * 16 + (lane & 15);
      int slot = (lane >> 4) ^ ((r + (r >> 2)) & 3);
      af[i] = *(const bf16x8*)(bufc + r * 64 + slot * 16);
    }
#pragma unroll
    for (int j = 0; j < 4; ++j) {
      int r = wid * 64 + j * 16 + (lane & 15);
      int slot = (lane >> 4) ^ ((r + (r >> 2)) & 3);
      bfr[j] = *(const bf16x8*)(bufc + 4096 + r * 64 + slot * 16);
    }
#pragma unroll
    for (int i = 0; i < 4; ++i)
#pragma unroll
      for (int j = 0; j < 4; ++j)
        acc[i][j] = __builtin_amdgcn_mfma_f32_16x16x32_bf16(af[i], bfr[j],
                                                            acc[i][j], 0, 0, 0);
    if (step < 7) *(uint4*)(bufn + ldsAoff) = pk8(na0, na1);
    __syncthreads();
  }

  const int rbase = (lane >> 4) * 4;
  const int cn = lane & 15;
#pragma unroll
  for (int i = 0; i < 4; ++i) {
#pragma unroll
    for (int j = 0; j < 4; ++j) {
      int col = N0 + wid * 64 + j * 16 + cn;
      float bs = bias[col];
#pragma unroll
      for (int r = 0; r < 4; ++r) {
        int row = M0 + i * 16 + rbase + r;
        float v = acc[i][j][r] + bs;
        if (col < DMODEL)
          out0[(size_t)row * DMODEL + col] = v;
        else
          out1[(size_t)row * DMODEL + (col - DMODEL)] =
              (ushort)bf16rne(silu_fast(v));
      }
    }
  }
}

// ---------------------------------------------------------------------------
// K2 fused_mid (512 thr, 72 KB LDS -> 2 blocks/CU): conv+silu -> xc tile,
// delta GEMM (single-buffered W_delta stream), BC GEMM (interleaved), scan
// pass1 with n-split (2 threads per d, 8 states each).
// LDS: @0 xc bf16 [64][32c] swz                        (32 KB)
//      @32768 B single 16KB -> delta fp16 [64][256] swz (spans to 65536)
//      @49152 WBC [32][32c] swz (16 KB, dies after GEMMs)
//      @65536 BC f32 [64][32]   (8 KB)
// ---------------------------------------------------------------------------
__global__ __launch_bounds__(512, 4) void fused_mid(
    const float* __restrict__ xin, const ushort* __restrict__ wdl,
    const ushort* __restrict__ wbc, const float* __restrict__ b_delta,
    const float* __restrict__ A_log, const float* __restrict__ conv_w,
    const float* __restrict__ conv_b, ushort* __restrict__ xc_g,
    ushort* __restrict__ dl_g, ushort* __restrict__ bc_g,
    float* __restrict__ hout, float* __restrict__ cumA) {
  __shared__ char smem[73728];
  const int tid = threadIdx.x, lane = tid & 63, wid = tid >> 6;
  const int b = blockIdx.x / NCHB, c = blockIdx.x % NCHB;
  const int l0 = c * LC;
  const size_t row0 = (size_t)b * LSEQ + l0;

  // ---- WBC staging (32 rows x 256) -> @49152
  {
#pragma unroll
    for (int cc = 0; cc < 2; ++cc) {
      int row = (wid * 2 + cc) * 2 + (lane >> 5);
      int cB = (lane & 31) ^ (row & 7);
      glds16(wbc + (size_t)row * 256 + cB * 8,
             smem + 49152 + (wid * 2 + cc) * 1024);
    }
  }
  // ---- W_delta k-step 0 -> @32768 (single buffer)
  stageB512(wdl, smem + 32768, 0, lane, wid);

  // ---- conv + silu -> xc tile + global (each thread 4 l-rows x 8 d)
  {
    const int dq = tid & 31;
    const int d0 = dq * 8;
    float w0[8], w1[8], w2[8], cb[8];
#pragma unroll
    for (int k = 0; k < 8; ++k) {
      w0[k] = conv_w[(d0 + k) * 3 + 0];
      w1[k] = conv_w[(d0 + k) * 3 + 1];
      w2[k] = conv_w[(d0 + k) * 3 + 2];
      cb[k] = conv_b[d0 + k];
    }
#pragma unroll
    for (int it = 0; it < 4; ++it) {
      const int lr = it * 16 + (tid >> 5);
      const int l = l0 + lr;
      const size_t bp = (row0 + lr) * DMODEL + d0;
      float4 zf = {0.f, 0.f, 0.f, 0.f};
      float4 m0 = zf, m1 = zf, p0 = zf, p1 = zf;
      if (l > 0) {
        m0 = *(const float4*)(xin + bp - DMODEL);
        m1 = *(const float4*)(xin + bp - DMODEL + 4);
      }
      float4 c0 = *(const float4*)(xin + bp);
      float4 c1 = *(const float4*)(xin + bp + 4);
      if (l < LSEQ - 1) {
        p0 = *(const float4*)(xin + bp + DMODEL);
        p1 = *(const float4*)(xin + bp + DMODEL + 4);
      }
      float mv[8] = {m0.x, m0.y, m0.z, m0.w, m1.x, m1.y, m1.z, m1.w};
      float cv[8] = {c0.x, c0.y, c0.z, c0.w, c1.x, c1.y, c1.z, c1.w};
      float pv[8] = {p0.x, p0.y, p0.z, p0.w, p1.x, p1.y, p1.z, p1.w};
      float ov[8];
#pragma unroll
      for (int k = 0; k < 8; ++k) {
        float o = fmaf(w0[k], mv[k], fmaf(w1[k], cv[k], fmaf(w2[k], pv[k], cb[k])));
        ov[k] = silu_fast(o);
      }
      uint4 r4;
      r4.x = pk2(ov[0], ov[1]);
      r4.y = pk2(ov[2], ov[3]);
      r4.z = pk2(ov[4], ov[5]);
      r4.w = pk2(ov[6], ov[7]);
      *(uint4*)(xc_g + bp) = r4;
      *(uint4*)(smem + lr * 512 + ((dq ^ (lr & 7)) * 16)) = r4;
    }
  }
  __syncthreads();  // xc tile + WBC + B-k0 ready

  // ---- delta GEMM (single-buf B) with BC GEMM interleaved
  f32x4 acc[4][2];
#pragma unroll
  for (int i = 0; i < 4; ++i)
#pragma unroll
    for (int j = 0; j < 2; ++j) acc[i][j] = {0.f, 0.f, 0.f, 0.f};
  f32x4 accbc = {0.f, 0.f, 0.f, 0.f};

  for (int step = 0; step < 8; ++step) {
    bf16x8 af[4], bfr[2];
#pragma unroll
    for (int i = 0; i < 4; ++i) {
      int r = i * 16 + (lane & 15);
      int sc = step * 4 + (lane >> 4);
      af[i] = *(const bf16x8*)(smem + r * 512 + ((sc ^ (r & 7)) * 16));
    }
#pragma unroll
    for (int j = 0; j < 2; ++j) {
      int r = wid * 32 + j * 16 + (lane & 15);
      int slot = (lane >> 4) ^ ((r + (r >> 2)) & 3);
      bfr[j] = *(const bf16x8*)(smem + 32768 + r * 64 + slot * 16);
    }
#pragma unroll
    for (int i = 0; i < 4; ++i)
#pragma unroll
      for (int j = 0; j < 2; ++j)
        acc[i][j] = __builtin_amdgcn_mfma_f32_16x16x32_bf16(af[i], bfr[j],
                                                            acc[i][j], 0, 0, 0);
    __syncthreads();  // all reads of B buffer done
    if (step < 7) stageB512(wdl, smem + 32768, (step + 1) * 32, lane, wid);
    {  // BC GEMM step (all 8 waves; wave w -> rows (w>>1)*16, col blk w&1)
      int sc = step * 4 + (lane >> 4);
      int ra = (wid >> 1) * 16 + (lane & 15);
      bf16x8 a2 = *(const bf16x8*)(smem + ra * 512 + ((sc ^ (ra & 7)) * 16));
      int br = (wid & 1) * 16 + (lane & 15);
      bf16x8 b2 =
          *(const bf16x8*)(smem + 49152 + br * 512 + ((sc ^ (br & 7)) * 16));
      accbc = __builtin_amdgcn_mfma_f32_16x16x32_bf16(a2, b2, accbc, 0, 0, 0);
    }
    __syncthreads();  // staged B visible
  }

  // ---- delta epilogue -> fp16 tile @32768 (over B + WBC), swz
  const int rbase = (lane >> 4) * 4;
  const int cn = lane & 15;
#pragma unroll
  for (int i = 0; i < 4; ++i)
#pragma unroll
    for (int j = 0; j < 2; ++j) {
      int col = wid * 32 + j * 16 + cn;
      float bs = b_delta[col];
#pragma unroll
      for (int r = 0; r < 4; ++r) {
        int row = i * 16 + rbase + r;
        *(ushort*)(smem + 32768 + row * 512 +
                   ((col * 2) ^ (((row >> 2) & 3) << 5))) =
            f2h(softplus_fast(acc[i][j][r] + bs));
      }
    }
  // ---- BC epilogue: BC f32 @65536 + bc_g
  {
#pragma unroll
    for (int r = 0; r < 4; ++r) {
      int row = (wid >> 1) * 16 + rbase + r;
      int col = (wid & 1) * 16 + cn;
      ushort bv = (ushort)bf16rne(accbc[r]);
      ((float*)(smem + 65536))[row * 32 + col] = bf2f(bv);
      bc_g[(row0 + row) * 32 + col] = bv;
    }
  }
  __syncthreads();  // delta tile + BC f32 visible

  // ---- dl_g coalesced write from delta tile
#pragma unroll
  for (int it = 0; it < 4; ++it) {
    int idx = it * 512 + tid;
    int row = idx >> 5, ch = idx & 31;
    *(uint4*)(dl_g + (row0 + row) * DMODEL + ch * 8) =
        *(const uint4*)(smem + 32768 + row * 512 +
                        ((ch ^ (((row >> 2) & 3) << 1)) * 16));
  }

  // ---- scan pass1, n-split: d = tid>>1, s = tid&1, states [8s, 8s+8)
  const int d = tid >> 1;
  const int s = tid & 1;
  float Aa2h[8];
  {
    float4 v0 = *(const float4*)(A_log + d * NST + 8 * s);
    float4 v1 = *(const float4*)(A_log + d * NST + 8 * s + 4);
    Aa2h[0] = -LOG2E * __expf(v0.x);
    Aa2h[1] = -LOG2E * __expf(v0.y);
    Aa2h[2] = -LOG2E * __expf(v0.z);
    Aa2h[3] = -LOG2E * __expf(v0.w);
    Aa2h[4] = -LOG2E * __expf(v1.x);
    Aa2h[5] = -LOG2E * __expf(v1.y);
    Aa2h[6] = -LOG2E * __expf(v1.z);
    Aa2h[7] = -LOG2E * __expf(v1.w);
  }
  const float Aa2_0 = -LOG2E * __expf(A_log[d * NST]);
  bool pm = true;
#pragma unroll
  for (int k = 0; k < 8; ++k)
    pm = pm && (fabsf(Aa2h[k] - (float)(8 * s + k + 1) * Aa2_0) <=
                1e-3f * fabsf(Aa2h[k]));

  float h[8];
#pragma unroll
  for (int k = 0; k < 8; ++k) h[k] = 0.f;
  float sdt = 0.f;
  const int uoff0 = (d & 7) * 2;
  const int uchunk = d >> 3;
  if (pm) {
#pragma unroll 4
    for (int l = 0; l < LC; ++l) {
      float dt = h2f(*(const ushort*)(smem + 32768 + l * 512 +
                                      ((d * 2) ^ (((l >> 2) & 3) << 5))));
      float u = bf2f(*(const ushort*)(smem + l * 512 +
                                      ((uchunk ^ (l & 7)) * 16) + uoff0));
      sdt += dt;
      float dtu = dt * u;
      const float* Bp = (const float*)(smem + 65536) + l * 32 + 8 * s;
      f32x4 B0 = *(const f32x4*)(Bp);
      f32x4 B1 = *(const f32x4*)(Bp + 4);
      float Bv[8] = {B0.x, B0.y, B0.z, B0.w, B1.x, B1.y, B1.z, B1.w};
      float p[8];
      pow8half(__builtin_amdgcn_exp2f(dt * Aa2_0), s, p);
#pragma unroll
      for (int k = 0; k < 8; ++k) h[k] = fmaf(p[k], h[k], dtu * Bv[k]);
    }
  } else {
#pragma unroll 4
    for (int l = 0; l < LC; ++l) {
      float dt = h2f(*(const ushort*)(smem + 32768 + l * 512 +
                                      ((d * 2) ^ (((l >> 2) & 3) << 5))));
      float u = bf2f(*(const ushort*)(smem + l * 512 +
                                      ((uchunk ^ (l & 7)) * 16) + uoff0));
      sdt += dt;
      float dtu = dt * u;
      const float* Bp = (const float*)(smem + 65536) + l * 32 + 8 * s;
      f32x4 B0 = *(const f32x4*)(Bp);
      f32x4 B1 = *(const f32x4*)(Bp + 4);
      float Bv[8] = {B0.x, B0.y, B0.z, B0.w, B1.x, B1.y, B1.z, B1.w};
#pragma unroll
      for (int k = 0; k < 8; ++k) {
        float ab = __builtin_amdgcn_exp2f(dt * Aa2h[k]);
        h[k] = fmaf(ab, h[k], dtu * Bv[k]);
      }
    }
  }
  float cum[8];
  if (pm) {
    pow8half(__builtin_amdgcn_exp2f(sdt * Aa2_0), s, cum);
  } else {
#pragma unroll
    for (int k = 0; k < 8; ++k)
      cum[k] = __builtin_amdgcn_exp2f(sdt * Aa2h[k]);
  }
  const size_t ob =
      (((size_t)(b * NCHB + c)) * DMODEL + d) * NST + 8 * s;
#pragma unroll
  for (int q = 0; q < 2; ++q) {
    float4 hv = {h[q * 4 + 0], h[q * 4 + 1], h[q * 4 + 2], h[q * 4 + 3]};
    *(float4*)(hout + ob + q * 4) = hv;
    float4 cvv = {cum[q * 4 + 0], cum[q * 4 + 1], cum[q * 4 + 2],
                  cum[q * 4 + 3]};
    *(float4*)(cumA + ob + q * 4) = cvv;
  }
}

// ---------------------------------------------------------------------------
// Scan combine over 64 chunks; in-place h_out -> h_in (fp32).
// ---------------------------------------------------------------------------
__global__ __launch_bounds__(256) void scan_combine(
    float* __restrict__ hstate, const float* __restrict__ cumA) {
  const int t = blockIdx.x * 256 + threadIdx.x;
  const int n = t & (NST - 1);
  const int dd = (t / NST) & (DMODEL - 1);
  const int b = t / (NST * DMODEL);
  float h = 0.f;
  for (int c = 0; c < NCHB; ++c) {
    size_t idx = (((size_t)(b * NCHB + c)) * DMODEL + dd) * NST + n;
    float ho = hstate[idx];
    float ca = cumA[idx];
    hstate[idx] = h;
    h = fmaf(ca, h, ho);
  }
}

// ---------------------------------------------------------------------------
// K3 fused_out (512 thr, 72 KB LDS): scan pass3 (n-split, shfl_xor y-combine)
// -> y_pre LDS tile -> GEMM with W_out (dbuf) -> d_out.
// LDS: @0 ypre bf16 [64][32c] swz (32 KB); @32768 B dbuf 16KBx2;
//      @65536 BC f32 [64][32] (8 KB).
// ---------------------------------------------------------------------------
__global__ __launch_bounds__(512, 4) void fused_out(
    const ushort* __restrict__ dl, const ushort* __restrict__ xcb,
    const ushort* __restrict__ szy, const ushort* __restrict__ bcb,
    const float* __restrict__ A_log, const float* __restrict__ hin,
    const float* __restrict__ Dskip, const ushort* __restrict__ wout,
    const float* __restrict__ b_out, float* __restrict__ out) {
  __shared__ char smem[73728];
  const int tid = threadIdx.x, lane = tid & 63, wid = tid >> 6;
  const int b = blockIdx.x / NCHB, c = blockIdx.x % NCHB;
  const int l0 = c * LC;
  const size_t row0 = (size_t)b * LSEQ + l0;

  // stage BC f32 tile (512 thr x 4 vals)
  {
    int r = tid >> 3, q = tid & 7;
    uint2 v = *(const uint2*)(bcb + (row0 + r) * 32 + q * 4);
    float* dp = (float*)(smem + 65536) + r * 32 + q * 4;
    dp[0] = bf2f((ushort)(v.x & 0xffff));
    dp[1] = bf2f((ushort)(v.x >> 16));
    dp[2] = bf2f((ushort)(v.y & 0xffff));
    dp[3] = bf2f((ushort)(v.y >> 16));
  }
  // issue W_out k-step 0
  stageB512(wout, smem + 32768, 0, lane, wid);

  // ---- scan setup (n-split)
  const int d = tid >> 1;
  const int s = tid & 1;
  float Aa2h[8];
  {
    float4 v0 = *(const float4*)(A_log + d * NST + 8 * s);
    float4 v1 = *(const float4*)(A_log + d * NST + 8 * s + 4);
    Aa2h[0] = -LOG2E * __expf(v0.x);
    Aa2h[1] = -LOG2E * __expf(v0.y);
    Aa2h[2] = -LOG2E * __expf(v0.z);
    Aa2h[3] = -LOG2E * __expf(v0.w);
    Aa2h[4] = -LOG2E * __expf(v1.x);
    Aa2h[5] = -LOG2E * __expf(v1.y);
    Aa2h[6] = -LOG2E * __expf(v1.z);
    Aa2h[7] = -LOG2E * __expf(v1.w);
  }
  const float Aa2_0 = -LOG2E * __expf(A_log[d * NST]);
  bool pm = true;
#pragma unroll
  for (int k = 0; k < 8; ++k)
    pm = pm && (fabsf(Aa2h[k] - (float)(8 * s + k + 1) * Aa2_0) <=
                1e-3f * fabsf(Aa2h[k]));
  float h[8];
  const size_t hb =
      (((size_t)(b * NCHB + c)) * DMODEL + d) * NST + 8 * s;
  {
    float4 v0 = *(const float4*)(hin + hb);
    float4 v1 = *(const float4*)(hin + hb + 4);
    h[0] = v0.x; h[1] = v0.y; h[2] = v0.z; h[3] = v0.w;
    h[4] = v1.x; h[5] = v1.y; h[6] = v1.z; h[7] = v1.w;
  }
  const float dsk = Dskip[d];
  __syncthreads();  // BC tile ready

  // ---- scan, y_pre -> LDS (both pair lanes write same value)
  const size_t base = row0 * DMODEL + d;
  const int ywoff = (d & 7) * 2;
  const int ywchunk = d >> 3;
  ushort dtr[4], ur[4], zr[4];
#pragma unroll
  for (int j = 0; j < 4; ++j) {
    dtr[j] = dl[base + (size_t)j * DMODEL];
    ur[j] = xcb[base + (size_t)j * DMODEL];
    zr[j] = szy[base + (size_t)j * DMODEL];
  }
  for (int lb = 0; lb < LC / 4; ++lb) {
    ushort dtn[4], un[4], zn[4];
    if (lb < LC / 4 - 1) {
      size_t nb = base + (size_t)(lb * 4 + 4) * DMODEL;
#pragma unroll
      for (int j = 0; j < 4; ++j) {
        dtn[j] = dl[nb + (size_t)j * DMODEL];
        un[j] = xcb[nb + (size_t)j * DMODEL];
        zn[j] = szy[nb + (size_t)j * DMODEL];
      }
    }
#pragma unroll
    for (int j = 0; j < 4; ++j) {
      int l = lb * 4 + j;
      float dt = h2f(dtr[j]);
      float u = bf2f(ur[j]);
      float dtu = dt * u;
      const float* Bp = (const float*)(smem + 65536) + l * 32 + 8 * s;
      f32x4 B0 = *(const f32x4*)(Bp);
      f32x4 B1 = *(const f32x4*)(Bp + 4);
      f32x4 C0 = *(const f32x4*)(Bp + 16);
      f32x4 C1 = *(const f32x4*)(Bp + 20);
      float Bv[8] = {B0.x, B0.y, B0.z, B0.w, B1.x, B1.y, B1.z, B1.w};
      float Cv[8] = {C0.x, C0.y, C0.z, C0.w, C1.x, C1.y, C1.z, C1.w};
      float y = 0.f;
      if (pm) {
        float p[8];
        pow8half(__builtin_amdgcn_exp2f(dt * Aa2_0), s, p);
#pragma unroll
        for (int k = 0; k < 8; ++k) {
          h[k] = fmaf(p[k], h[k], dtu * Bv[k]);
          y = fmaf(h[k], Cv[k], y);
        }
      } else {
#pragma unroll
        for (int k = 0; k < 8; ++k) {
          float ab = __builtin_amdgcn_exp2f(dt * Aa2h[k]);
          h[k] = fmaf(ab, h[k], dtu * Bv[k]);
          y = fmaf(h[k], Cv[k], y);
        }
      }
      y += __shfl_xor(y, 1);  // combine the two n-halves (adjacent lanes)
      float yp = (y + u * dsk) * bf2f(zr[j]);
      *(ushort*)(smem + l * 512 + ((ywchunk ^ (l & 7)) * 16) + ywoff) =
          (ushort)bf16rne(yp);
    }
#pragma unroll
    for (int j = 0; j < 4; ++j) {
      dtr[j] = dtn[j];
      ur[j] = un[j];
      zr[j] = zn[j];
    }
  }
  __syncthreads();  // ypre tile complete

  // ---- output GEMM: wave w -> cols w*32; acc 4x2; dbuf B
  f32x4 acc[4][2];
#pragma unroll
  for (int i = 0; i < 4; ++i)
#pragma unroll
    for (int j = 0; j < 2; ++j) acc[i][j] = {0.f, 0.f, 0.f, 0.f};

  for (int step = 0; step < 8; ++step) {
    char* bufc = smem + 32768 + (step & 1) * 16384;
    if (step < 7)
      stageB512(wout, smem + 32768 + ((step + 1) & 1) * 16384,
                (step + 1) * 32, lane, wid);
    bf16x8 af[4], bfr[2];
#pragma unroll
    for (int i = 0; i < 4; ++i) {
      int r = i * 16 + (lane & 15);
      int sc = step * 4 + (lane >> 4);
      af[i] = *(const bf16x8*)(smem + r * 512 + ((sc ^ (r & 7)) * 16));
    }
#pragma unroll
    for (int j = 0; j < 2; ++j) {
      int r = wid * 32 + j * 16 + (lane & 15);
      int slot = (lane >> 4) ^ ((r + (r >> 2)) & 3);
      bfr[j] = *(const bf16x8*)(bufc + r * 64 + slot * 16);
    }
#pragma unroll
    for (int i = 0; i < 4; ++i)
#pragma unroll
      for (int j = 0; j < 2; ++j)
        acc[i][j] = __builtin_amdgcn_mfma_f32_16x16x32_bf16(af[i], bfr[j],
                                                            acc[i][j], 0, 0, 0);
    __syncthreads();
  }

  const int rbase = (lane >> 4) * 4;
  const int cn = lane & 15;
#pragma unroll
  for (int i = 0; i < 4; ++i)
#pragma unroll
    for (int j = 0; j < 2; ++j) {
      int col = wid * 32 + j * 16 + cn;
      float bs = b_out[col];
#pragma unroll
      for (int r = 0; r < 4; ++r) {
        int row = i * 16 + rbase + r;
        out[(row0 + row) * DMODEL + col] = acc[i][j][r] + bs;
      }
    }
}

// ---------------------------------------------------------------------------
extern "C" void kernel_launch(void* const* d_in, const int* in_sizes, int n_in,
                              void* d_out, int out_size, void* d_ws,
                              size_t ws_size, hipStream_t stream) {
  const float* x       = (const float*)d_in[0];
  const float* A_log   = (const float*)d_in[1];
  const float* D_skip  = (const float*)d_in[2];
  const float* W_B     = (const float*)d_in[3];
  const float* W_C     = (const float*)d_in[4];
  const float* W_delta = (const float*)d_in[5];
  const float* b_delta = (const float*)d_in[6];
  const float* W_in    = (const float*)d_in[7];
  const float* b_in    = (const float*)d_in[8];
  const float* W_out   = (const float*)d_in[9];
  const float* b_out   = (const float*)d_in[10];
  const float* conv_w  = (const float*)d_in[11];
  const float* conv_b  = (const float*)d_in[12];

  const size_t MD = (size_t)MROWS * DMODEL;                // 16.78M
  const size_t HP = (size_t)BATCH * NCHB * DMODEL * NST;   // 4.19M
  float* xin   = (float*)d_ws;              // x_in fp32 [MD]
  ushort* dl   = (ushort*)(xin + MD);       // delta fp16 [MD]
  ushort* szy  = dl + MD;                   // silu(z) bf16 [MD]
  ushort* xcb  = szy + MD;                  // xc bf16 [MD]
  ushort* bcb  = xcb + MD;                  // bc bf16 [MROWS*32]
  float* hst   = (float*)(bcb + (size_t)MROWS * 32);  // h_out -> h_in [HP]
  float* cumA  = hst + HP;                  // [HP]
  ushort* wbf  = (ushort*)(cumA + HP);      // bf16 weights, 270336

  cvt_weights<<<dim3(132), 256, 0, stream>>>(W_in, W_delta, W_out, W_B, W_C, wbf);
  gemm_in<<<dim3(2, MROWS / 64), 256, 0, stream>>>(x, wbf, b_in, xin, szy);
  fused_mid<<<dim3(BATCH * NCHB), 512, 0, stream>>>(
      xin, wbf + 131072, wbf + 262144, b_delta, A_log, conv_w, conv_b,
      xcb, dl, bcb, hst, cumA);
  scan_combine<<<dim3(BATCH * DMODEL * NST / 256), 256, 0, stream>>>(hst, cumA);
  fused_out<<<dim3(BATCH * NCHB), 512, 0, stream>>>(
      dl, xcb, szy, bcb, A_log, hst, D_skip, wbf + 196608, b_out,
      (float*)d_out);
}

// Round 12
// 198.772 us; speedup vs baseline: 1.2832x; 1.0298x over previous
//
#include <hip/hip_runtime.h>
#include <hip/hip_bf16.h>
#include <math.h>

#define BATCH 16
#define LSEQ 4096
#define DMODEL 256
#define NST 16
#define LC 64                   // rows per fused block / scan chunk
#define NCHB (LSEQ / LC)        // 64 chunks per batch
#define MROWS (BATCH * LSEQ)    // 65536
#define LOG2E 1.44269504088896340736f
#define LN2 0.6931471805599453f

typedef float f32x4 __attribute__((ext_vector_type(4)));
typedef short bf16x8 __attribute__((ext_vector_type(8)));

__device__ __forceinline__ float silu_fast(float v) {
  return v * __builtin_amdgcn_rcpf(1.f + __builtin_amdgcn_exp2f(-v * LOG2E));
}
__device__ __forceinline__ float softplus_fast(float v) {
  float l = LN2 * __builtin_amdgcn_logf(1.f + __builtin_amdgcn_exp2f(v * LOG2E));
  return v > 16.f ? v : l;
}
__device__ __forceinline__ uint bf16rne(float f) {
  uint u = __float_as_uint(f);
  return (u + 0x7fffu + ((u >> 16) & 1u)) >> 16;
}
__device__ __forceinline__ float bf2f(ushort u) {
  return __uint_as_float((uint)u << 16);
}
__device__ __forceinline__ ushort f2h(float v) {
  _Float16 h = (_Float16)v;
  return __builtin_bit_cast(ushort, h);
}
__device__ __forceinline__ float h2f(ushort u) {
  return (float)__builtin_bit_cast(_Float16, u);
}
__device__ __forceinline__ uint pk2(float x, float y) {
  return bf16rne(x) | (bf16rne(y) << 16);
}
__device__ __forceinline__ uint4 pk8(float4 a, float4 b) {
  uint4 r;
  r.x = pk2(a.x, a.y);
  r.y = pk2(a.z, a.w);
  r.z = pk2(b.x, b.y);
  r.w = pk2(b.z, b.w);
  return r;
}
// unpack 8 bf16 (uint4) -> 8 floats
__device__ __forceinline__ void ub8(uint4 v, float* o) {
  o[0] = bf2f((ushort)(v.x & 0xffff));
  o[1] = bf2f((ushort)(v.x >> 16));
  o[2] = bf2f((ushort)(v.y & 0xffff));
  o[3] = bf2f((ushort)(v.y >> 16));
  o[4] = bf2f((ushort)(v.z & 0xffff));
  o[5] = bf2f((ushort)(v.z >> 16));
  o[6] = bf2f((ushort)(v.w & 0xffff));
  o[7] = bf2f((ushort)(v.w >> 16));
}

// p[k] = e1^(k+1+8s): powers 1..8 of e1, times e8 when s==1.
__device__ __forceinline__ void pow8half(float e1, int s, float* p) {
  float e2 = e1 * e1, e4 = e2 * e2, e8 = e4 * e4;
  p[0] = e1;
  p[1] = e2;
  p[2] = e2 * e1;
  p[3] = e4;
  p[4] = e4 * e1;
  p[5] = e4 * e2;
  p[6] = e4 * p[2];
  p[7] = e8;
  float sel = s ? e8 : 1.0f;
#pragma unroll
  for (int k = 0; k < 8; ++k) p[k] *= sel;
}

// async global(bf16)->LDS, 16 B per lane
__device__ __forceinline__ void glds16(const ushort* g, char* l) {
  __builtin_amdgcn_global_load_lds(
      (const __attribute__((address_space(1))) void*)g,
      (__attribute__((address_space(3))) void*)l, 16, 0, 0);
}

// stage a 256x32 bf16 B k-slice (swizzled layout r*64 + slot*16,
// slot = chunk ^ ((r+(r>>2))&3)); 512 thr: wave w covers 1KB blocks 2w,2w+1.
__device__ __forceinline__ void stageB512(const ushort* gbase, char* dst,
                                          int k0, int lane, int wid) {
#pragma unroll
  for (int c = 0; c < 2; ++c) {
    int r = (wid * 2 + c) * 16 + (lane >> 2);
    int sA = (r + (r >> 2)) & 3;
    int cA = (lane & 3) ^ sA;
    glds16(gbase + (size_t)r * 256 + cA * 8 + k0, dst + (wid * 2 + c) * 1024);
  }
}

// ---------------------------------------------------------------------------
// Weight fp32->bf16 convert (layout unchanged).
// ---------------------------------------------------------------------------
__global__ __launch_bounds__(256) void cvt_weights(
    const float* __restrict__ Win, const float* __restrict__ Wd,
    const float* __restrict__ Wo, const float* __restrict__ WB,
    const float* __restrict__ WC, ushort* __restrict__ dst) {
  size_t i = ((size_t)blockIdx.x * 256 + threadIdx.x) * 8;
  if (i >= 270336) return;
  const float* s;
  size_t o;
  if (i < 131072)      { s = Win; o = i; }
  else if (i < 196608) { s = Wd;  o = i - 131072; }
  else if (i < 262144) { s = Wo;  o = i - 196608; }
  else if (i < 266240) { s = WB;  o = i - 262144; }
  else                 { s = WC;  o = i - 266240; }
  float4 a = *(const float4*)(s + o);
  float4 b = *(const float4*)(s + o + 4);
  *(uint4*)(dst + i) = pk8(a, b);
}

// ---------------------------------------------------------------------------
// gemm_in: xz = x @ W_in^T + b_in. Tile 64x256, grid (2, M/64);
// col<256 -> x_in bf16, col>=256 -> silu(z) bf16.
// ---------------------------------------------------------------------------
__global__ __launch_bounds__(256, 4) void gemm_in(
    const float* __restrict__ A, const ushort* __restrict__ Bbf,
    const float* __restrict__ bias, ushort* __restrict__ out0,
    ushort* __restrict__ out1) {
  constexpr int KD = 256;
  __shared__ char smem[40960];
  const int tid = threadIdx.x;
  const int lane = tid & 63, wid = tid >> 6;
  const int M0 = blockIdx.y * 64;
  const int N0 = blockIdx.x * 256;

  const int rA = tid >> 2, cA = tid & 3;
  const int sA = (rA + (rA >> 2)) & 3;
  const int ldsAoff = rA * 64 + ((cA ^ sA) * 16);
  const float* gA32 = A + (size_t)(M0 + rA) * KD + cA * 8;
  const ushort* gB = Bbf + (size_t)(N0 + rA) * KD + ((cA ^ sA) * 8);

  f32x4 acc[4][4];
#pragma unroll
  for (int i = 0; i < 4; ++i)
#pragma unroll
    for (int j = 0; j < 4; ++j) acc[i][j] = {0.f, 0.f, 0.f, 0.f};

  {
#pragma unroll
    for (int i = 0; i < 4; ++i)
      glds16(gB + (size_t)i * 64 * KD, smem + 4096 + i * 4096 + wid * 1024);
    float4 a0 = *(const float4*)(gA32);
    float4 a1 = *(const float4*)(gA32 + 4);
    *(uint4*)(smem + ldsAoff) = pk8(a0, a1);
  }
  __syncthreads();

  for (int step = 0; step < 8; ++step) {
    const int cur = step & 1;
    char* bufc = smem + cur * 20480;
    char* bufn = smem + (cur ^ 1) * 20480;
    float4 na0, na1;
    if (step < 7) {
      const int k0 = (step + 1) * 32;
#pragma unroll
      for (int i = 0; i < 4; ++i)
        glds16(gB + (size_t)i * 64 * KD + k0,
               bufn + 4096 + i * 4096 + wid * 1024);
      na0 = *(const float4*)(gA32 + k0);
      na1 = *(const float4*)(gA32 + k0 + 4);
    }
    bf16x8 af[4], bfr[4];
#pragma unroll
    for (int i = 0; i < 4; ++i) {
      int r = i * 16 + (lane & 15);
      int slot = (lane >> 4) ^ ((r + (r >> 2)) & 3);
      af[i] = *(const bf16x8*)(bufc + r * 64 + slot * 16);
    }
#pragma unroll
    for (int j = 0; j < 4; ++j) {
      int r = wid * 64 + j * 16 + (lane & 15);
      int slot = (lane >> 4) ^ ((r + (r >> 2)) & 3);
      bfr[j] = *(const bf16x8*)(bufc + 4096 + r * 64 + slot * 16);
    }
#pragma unroll
    for (int i = 0; i < 4; ++i)
#pragma unroll
      for (int j = 0; j < 4; ++j)
        acc[i][j] = __builtin_amdgcn_mfma_f32_16x16x32_bf16(af[i], bfr[j],
                                                            acc[i][j], 0, 0, 0);
    if (step < 7) *(uint4*)(bufn + ldsAoff) = pk8(na0, na1);
    __syncthreads();
  }

  const int rbase = (lane >> 4) * 4;
  const int cn = lane & 15;
#pragma unroll
  for (int i = 0; i < 4; ++i) {
#pragma unroll
    for (int j = 0; j < 4; ++j) {
      int col = N0 + wid * 64 + j * 16 + cn;
      float bs = bias[col];
#pragma unroll
      for (int r = 0; r < 4; ++r) {
        int row = M0 + i * 16 + rbase + r;
        float v = acc[i][j][r] + bs;
        if (col < DMODEL)
          out0[(size_t)row * DMODEL + col] = (ushort)bf16rne(v);
        else
          out1[(size_t)row * DMODEL + (col - DMODEL)] =
              (ushort)bf16rne(silu_fast(v));
      }
    }
  }
}

// ---------------------------------------------------------------------------
// K2 fused_mid (512 thr, 72 KB LDS): conv+silu -> xc tile, delta GEMM
// (single-buffered W_delta), BC GEMM (interleaved), scan pass1 n-split.
// xin now bf16.
// ---------------------------------------------------------------------------
__global__ __launch_bounds__(512, 4) void fused_mid(
    const ushort* __restrict__ xin, const ushort* __restrict__ wdl,
    const ushort* __restrict__ wbc, const float* __restrict__ b_delta,
    const float* __restrict__ A_log, const float* __restrict__ conv_w,
    const float* __restrict__ conv_b, ushort* __restrict__ xc_g,
    ushort* __restrict__ dl_g, ushort* __restrict__ bc_g,
    float* __restrict__ hout, float* __restrict__ cumA) {
  __shared__ char smem[73728];
  const int tid = threadIdx.x, lane = tid & 63, wid = tid >> 6;
  const int b = blockIdx.x / NCHB, c = blockIdx.x % NCHB;
  const int l0 = c * LC;
  const size_t row0 = (size_t)b * LSEQ + l0;

  // ---- WBC staging -> @49152
  {
#pragma unroll
    for (int cc = 0; cc < 2; ++cc) {
      int row = (wid * 2 + cc) * 2 + (lane >> 5);
      int cB = (lane & 31) ^ (row & 7);
      glds16(wbc + (size_t)row * 256 + cB * 8,
             smem + 49152 + (wid * 2 + cc) * 1024);
    }
  }
  // ---- W_delta k-step 0 -> @32768
  stageB512(wdl, smem + 32768, 0, lane, wid);

  // ---- conv + silu -> xc tile + global (each thread 4 l-rows x 8 d)
  {
    const int dq = tid & 31;
    const int d0 = dq * 8;
    float w0[8], w1[8], w2[8], cb[8];
#pragma unroll
    for (int k = 0; k < 8; ++k) {
      w0[k] = conv_w[(d0 + k) * 3 + 0];
      w1[k] = conv_w[(d0 + k) * 3 + 1];
      w2[k] = conv_w[(d0 + k) * 3 + 2];
      cb[k] = conv_b[d0 + k];
    }
#pragma unroll
    for (int it = 0; it < 4; ++it) {
      const int lr = it * 16 + (tid >> 5);
      const int l = l0 + lr;
      const size_t bp = (row0 + lr) * DMODEL + d0;
      uint4 zf4 = {0u, 0u, 0u, 0u};
      uint4 um = (l > 0) ? *(const uint4*)(xin + bp - DMODEL) : zf4;
      uint4 uc4 = *(const uint4*)(xin + bp);
      uint4 up = (l < LSEQ - 1) ? *(const uint4*)(xin + bp + DMODEL) : zf4;
      float mv[8], cv[8], pv[8], ov[8];
      ub8(um, mv);
      ub8(uc4, cv);
      ub8(up, pv);
#pragma unroll
      for (int k = 0; k < 8; ++k) {
        float o = fmaf(w0[k], mv[k], fmaf(w1[k], cv[k], fmaf(w2[k], pv[k], cb[k])));
        ov[k] = silu_fast(o);
      }
      uint4 r4;
      r4.x = pk2(ov[0], ov[1]);
      r4.y = pk2(ov[2], ov[3]);
      r4.z = pk2(ov[4], ov[5]);
      r4.w = pk2(ov[6], ov[7]);
      *(uint4*)(xc_g + bp) = r4;
      *(uint4*)(smem + lr * 512 + ((dq ^ (lr & 7)) * 16)) = r4;
    }
  }
  __syncthreads();  // xc tile + WBC + B-k0 ready

  // ---- delta GEMM (single-buf B) with BC GEMM interleaved
  f32x4 acc[4][2];
#pragma unroll
  for (int i = 0; i < 4; ++i)
#pragma unroll
    for (int j = 0; j < 2; ++j) acc[i][j] = {0.f, 0.f, 0.f, 0.f};
  f32x4 accbc = {0.f, 0.f, 0.f, 0.f};

  for (int step = 0; step < 8; ++step) {
    bf16x8 af[4], bfr[2];
#pragma unroll
    for (int i = 0; i < 4; ++i) {
      int r = i * 16 + (lane & 15);
      int sc = step * 4 + (lane >> 4);
      af[i] = *(const bf16x8*)(smem + r * 512 + ((sc ^ (r & 7)) * 16));
    }
#pragma unroll
    for (int j = 0; j < 2; ++j) {
      int r = wid * 32 + j * 16 + (lane & 15);
      int slot = (lane >> 4) ^ ((r + (r >> 2)) & 3);
      bfr[j] = *(const bf16x8*)(smem + 32768 + r * 64 + slot * 16);
    }
#pragma unroll
    for (int i = 0; i < 4; ++i)
#pragma unroll
      for (int j = 0; j < 2; ++j)
        acc[i][j] = __builtin_amdgcn_mfma_f32_16x16x32_bf16(af[i], bfr[j],
                                                            acc[i][j], 0, 0, 0);
    __syncthreads();  // all reads of B buffer done
    if (step < 7) stageB512(wdl, smem + 32768, (step + 1) * 32, lane, wid);
    {  // BC GEMM step
      int sc = step * 4 + (lane >> 4);
      int ra = (wid >> 1) * 16 + (lane & 15);
      bf16x8 a2 = *(const bf16x8*)(smem + ra * 512 + ((sc ^ (ra & 7)) * 16));
      int br = (wid & 1) * 16 + (lane & 15);
      bf16x8 b2 =
          *(const bf16x8*)(smem + 49152 + br * 512 + ((sc ^ (br & 7)) * 16));
      accbc = __builtin_amdgcn_mfma_f32_16x16x32_bf16(a2, b2, accbc, 0, 0, 0);
    }
    __syncthreads();  // staged B visible
  }

  // ---- delta epilogue -> fp16 tile @32768, swz
  const int rbase = (lane >> 4) * 4;
  const int cn = lane & 15;
#pragma unroll
  for (int i = 0; i < 4; ++i)
#pragma unroll
    for (int j = 0; j < 2; ++j) {
      int col = wid * 32 + j * 16 + cn;
      float bs = b_delta[col];
#pragma unroll
      for (int r = 0; r < 4; ++r) {
        int row = i * 16 + rbase + r;
        *(ushort*)(smem + 32768 + row * 512 +
                   ((col * 2) ^ (((row >> 2) & 3) << 5))) =
            f2h(softplus_fast(acc[i][j][r] + bs));
      }
    }
  // ---- BC epilogue
  {
#pragma unroll
    for (int r = 0; r < 4; ++r) {
      int row = (wid >> 1) * 16 + rbase + r;
      int col = (wid & 1) * 16 + cn;
      ushort bv = (ushort)bf16rne(accbc[r]);
      ((float*)(smem + 65536))[row * 32 + col] = bf2f(bv);
      bc_g[(row0 + row) * 32 + col] = bv;
    }
  }
  __syncthreads();

  // ---- dl_g coalesced write
#pragma unroll
  for (int it = 0; it < 4; ++it) {
    int idx = it * 512 + tid;
    int row = idx >> 5, ch = idx & 31;
    *(uint4*)(dl_g + (row0 + row) * DMODEL + ch * 8) =
        *(const uint4*)(smem + 32768 + row * 512 +
                        ((ch ^ (((row >> 2) & 3) << 1)) * 16));
  }

  // ---- scan pass1, n-split
  const int d = tid >> 1;
  const int s = tid & 1;
  float Aa2h[8];
  {
    float4 v0 = *(const float4*)(A_log + d * NST + 8 * s);
    float4 v1 = *(const float4*)(A_log + d * NST + 8 * s + 4);
    Aa2h[0] = -LOG2E * __expf(v0.x);
    Aa2h[1] = -LOG2E * __expf(v0.y);
    Aa2h[2] = -LOG2E * __expf(v0.z);
    Aa2h[3] = -LOG2E * __expf(v0.w);
    Aa2h[4] = -LOG2E * __expf(v1.x);
    Aa2h[5] = -LOG2E * __expf(v1.y);
    Aa2h[6] = -LOG2E * __expf(v1.z);
    Aa2h[7] = -LOG2E * __expf(v1.w);
  }
  const float Aa2_0 = -LOG2E * __expf(A_log[d * NST]);
  bool pm = true;
#pragma unroll
  for (int k = 0; k < 8; ++k)
    pm = pm && (fabsf(Aa2h[k] - (float)(8 * s + k + 1) * Aa2_0) <=
                1e-3f * fabsf(Aa2h[k]));

  float h[8];
#pragma unroll
  for (int k = 0; k < 8; ++k) h[k] = 0.f;
  float sdt = 0.f;
  const int uoff0 = (d & 7) * 2;
  const int uchunk = d >> 3;
  if (pm) {
#pragma unroll 4
    for (int l = 0; l < LC; ++l) {
      float dt = h2f(*(const ushort*)(smem + 32768 + l * 512 +
                                      ((d * 2) ^ (((l >> 2) & 3) << 5))));
      float u = bf2f(*(const ushort*)(smem + l * 512 +
                                      ((uchunk ^ (l & 7)) * 16) + uoff0));
      sdt += dt;
      float dtu = dt * u;
      const float* Bp = (const float*)(smem + 65536) + l * 32 + 8 * s;
      f32x4 B0 = *(const f32x4*)(Bp);
      f32x4 B1 = *(const f32x4*)(Bp + 4);
      float Bv[8] = {B0.x, B0.y, B0.z, B0.w, B1.x, B1.y, B1.z, B1.w};
      float p[8];
      pow8half(__builtin_amdgcn_exp2f(dt * Aa2_0), s, p);
#pragma unroll
      for (int k = 0; k < 8; ++k) h[k] = fmaf(p[k], h[k], dtu * Bv[k]);
    }
  } else {
#pragma unroll 4
    for (int l = 0; l < LC; ++l) {
      float dt = h2f(*(const ushort*)(smem + 32768 + l * 512 +
                                      ((d * 2) ^ (((l >> 2) & 3) << 5))));
      float u = bf2f(*(const ushort*)(smem + l * 512 +
                                      ((uchunk ^ (l & 7)) * 16) + uoff0));
      sdt += dt;
      float dtu = dt * u;
      const float* Bp = (const float*)(smem + 65536) + l * 32 + 8 * s;
      f32x4 B0 = *(const f32x4*)(Bp);
      f32x4 B1 = *(const f32x4*)(Bp + 4);
      float Bv[8] = {B0.x, B0.y, B0.z, B0.w, B1.x, B1.y, B1.z, B1.w};
#pragma unroll
      for (int k = 0; k < 8; ++k) {
        float ab = __builtin_amdgcn_exp2f(dt * Aa2h[k]);
        h[k] = fmaf(ab, h[k], dtu * Bv[k]);
      }
    }
  }
  float cum[8];
  if (pm) {
    pow8half(__builtin_amdgcn_exp2f(sdt * Aa2_0), s, cum);
  } else {
#pragma unroll
    for (int k = 0; k < 8; ++k)
      cum[k] = __builtin_amdgcn_exp2f(sdt * Aa2h[k]);
  }
  const size_t ob =
      (((size_t)(b * NCHB + c)) * DMODEL + d) * NST + 8 * s;
#pragma unroll
  for (int q = 0; q < 2; ++q) {
    float4 hv = {h[q * 4 + 0], h[q * 4 + 1], h[q * 4 + 2], h[q * 4 + 3]};
    *(float4*)(hout + ob + q * 4) = hv;
    float4 cvv = {cum[q * 4 + 0], cum[q * 4 + 1], cum[q * 4 + 2],
                  cum[q * 4 + 3]};
    *(float4*)(cumA + ob + q * 4) = cvv;
  }
}

// ---------------------------------------------------------------------------
// Scan combine over 64 chunks; in-place h_out -> h_in.
// ---------------------------------------------------------------------------
__global__ __launch_bounds__(256) void scan_combine(
    float* __restrict__ hstate, const float* __restrict__ cumA) {
  const int t = blockIdx.x * 256 + threadIdx.x;
  const int n = t & (NST - 1);
  const int dd = (t / NST) & (DMODEL - 1);
  const int b = t / (NST * DMODEL);
  float h = 0.f;
  for (int c = 0; c < NCHB; ++c) {
    size_t idx = (((size_t)(b * NCHB + c)) * DMODEL + dd) * NST + n;
    float ho = hstate[idx];
    float ca = cumA[idx];
    hstate[idx] = h;
    h = fmaf(ca, h, ho);
  }
}

// ---------------------------------------------------------------------------
// K3 fused_out (512 thr, 72 KB LDS): scan pass3 (n-split; s=0 lane owns
// z-load + yp + LDS write) -> y_pre tile -> GEMM W_out -> d_out.
// ---------------------------------------------------------------------------
__global__ __launch_bounds__(512, 4) void fused_out(
    const ushort* __restrict__ dl, const ushort* __restrict__ xcb,
    const ushort* __restrict__ szy, const ushort* __restrict__ bcb,
    const float* __restrict__ A_log, const float* __restrict__ hin,
    const float* __restrict__ Dskip, const ushort* __restrict__ wout,
    const float* __restrict__ b_out, float* __restrict__ out) {
  __shared__ char smem[73728];
  const int tid = threadIdx.x, lane = tid & 63, wid = tid >> 6;
  const int b = blockIdx.x / NCHB, c = blockIdx.x % NCHB;
  const int l0 = c * LC;
  const size_t row0 = (size_t)b * LSEQ + l0;

  // stage BC f32 tile
  {
    int r = tid >> 3, q = tid & 7;
    uint2 v = *(const uint2*)(bcb + (row0 + r) * 32 + q * 4);
    float* dp = (float*)(smem + 65536) + r * 32 + q * 4;
    dp[0] = bf2f((ushort)(v.x & 0xffff));
    dp[1] = bf2f((ushort)(v.x >> 16));
    dp[2] = bf2f((ushort)(v.y & 0xffff));
    dp[3] = bf2f((ushort)(v.y >> 16));
  }
  // issue W_out k-step 0
  stageB512(wout, smem + 32768, 0, lane, wid);

  // ---- scan setup (n-split)
  const int d = tid >> 1;
  const int s = tid & 1;
  float Aa2h[8];
  {
    float4 v0 = *(const float4*)(A_log + d * NST + 8 * s);
    float4 v1 = *(const float4*)(A_log + d * NST + 8 * s + 4);
    Aa2h[0] = -LOG2E * __expf(v0.x);
    Aa2h[1] = -LOG2E * __expf(v0.y);
    Aa2h[2] = -LOG2E * __expf(v0.z);
    Aa2h[3] = -LOG2E * __expf(v0.w);
    Aa2h[4] = -LOG2E * __expf(v1.x);
    Aa2h[5] = -LOG2E * __expf(v1.y);
    Aa2h[6] = -LOG2E * __expf(v1.z);
    Aa2h[7] = -LOG2E * __expf(v1.w);
  }
  const float Aa2_0 = -LOG2E * __expf(A_log[d * NST]);
  bool pm = true;
#pragma unroll
  for (int k = 0; k < 8; ++k)
    pm = pm && (fabsf(Aa2h[k] - (float)(8 * s + k + 1) * Aa2_0) <=
                1e-3f * fabsf(Aa2h[k]));
  float h[8];
  const size_t hb =
      (((size_t)(b * NCHB + c)) * DMODEL + d) * NST + 8 * s;
  {
    float4 v0 = *(const float4*)(hin + hb);
    float4 v1 = *(const float4*)(hin + hb + 4);
    h[0] = v0.x; h[1] = v0.y; h[2] = v0.z; h[3] = v0.w;
    h[4] = v1.x; h[5] = v1.y; h[6] = v1.z; h[7] = v1.w;
  }
  const float dsk = Dskip[d];
  __syncthreads();  // BC tile ready

  // ---- scan, y_pre -> LDS (s=0 lane finishes + writes)
  const size_t base = row0 * DMODEL + d;
  const int ywoff = (d & 7) * 2;
  const int ywchunk = d >> 3;
  ushort dtr[4], ur[4], zr[4];
#pragma unroll
  for (int j = 0; j < 4; ++j) {
    dtr[j] = dl[base + (size_t)j * DMODEL];
    ur[j] = xcb[base + (size_t)j * DMODEL];
    if (s == 0) zr[j] = szy[base + (size_t)j * DMODEL];
  }
  for (int lb = 0; lb < LC / 4; ++lb) {
    ushort dtn[4], un[4], zn[4];
    if (lb < LC / 4 - 1) {
      size_t nb = base + (size_t)(lb * 4 + 4) * DMODEL;
#pragma unroll
      for (int j = 0; j < 4; ++j) {
        dtn[j] = dl[nb + (size_t)j * DMODEL];
        un[j] = xcb[nb + (size_t)j * DMODEL];
        if (s == 0) zn[j] = szy[nb + (size_t)j * DMODEL];
      }
    }
#pragma unroll
    for (int j = 0; j < 4; ++j) {
      int l = lb * 4 + j;
      float dt = h2f(dtr[j]);
      float u = bf2f(ur[j]);
      float dtu = dt * u;
      const float* Bp = (const float*)(smem + 65536) + l * 32 + 8 * s;
      f32x4 B0 = *(const f32x4*)(Bp);
      f32x4 B1 = *(const f32x4*)(Bp + 4);
      f32x4 C0 = *(const f32x4*)(Bp + 16);
      f32x4 C1 = *(const f32x4*)(Bp + 20);
      float Bv[8] = {B0.x, B0.y, B0.z, B0.w, B1.x, B1.y, B1.z, B1.w};
      float Cv[8] = {C0.x, C0.y, C0.z, C0.w, C1.x, C1.y, C1.z, C1.w};
      float y = 0.f;
      if (pm) {
        float p[8];
        pow8half(__builtin_amdgcn_exp2f(dt * Aa2_0), s, p);
#pragma unroll
        for (int k = 0; k < 8; ++k) {
          h[k] = fmaf(p[k], h[k], dtu * Bv[k]);
          y = fmaf(h[k], Cv[k], y);
        }
      } else {
#pragma unroll
        for (int k = 0; k < 8; ++k) {
          float ab = __builtin_amdgcn_exp2f(dt * Aa2h[k]);
          h[k] = fmaf(ab, h[k], dtu * Bv[k]);
          y = fmaf(h[k], Cv[k], y);
        }
      }
      y += __shfl_xor(y, 1);  // combine the two n-halves
      if (s == 0) {
        float yp = (y + u * dsk) * bf2f(zr[j]);
        *(ushort*)(smem + l * 512 + ((ywchunk ^ (l & 7)) * 16) + ywoff) =
            (ushort)bf16rne(yp);
      }
    }
#pragma unroll
    for (int j = 0; j < 4; ++j) {
      dtr[j] = dtn[j];
      ur[j] = un[j];
      if (s == 0) zr[j] = zn[j];
    }
  }
  __syncthreads();  // ypre tile complete

  // ---- output GEMM: wave w -> cols w*32; acc 4x2; dbuf B
  f32x4 acc[4][2];
#pragma unroll
  for (int i = 0; i < 4; ++i)
#pragma unroll
    for (int j = 0; j < 2; ++j) acc[i][j] = {0.f, 0.f, 0.f, 0.f};

  for (int step = 0; step < 8; ++step) {
    char* bufc = smem + 32768 + (step & 1) * 16384;
    if (step < 7)
      stageB512(wout, smem + 32768 + ((step + 1) & 1) * 16384,
                (step + 1) * 32, lane, wid);
    bf16x8 af[4], bfr[2];
#pragma unroll
    for (int i = 0; i < 4; ++i) {
      int r = i * 16 + (lane & 15);
      int sc = step * 4 + (lane >> 4);
      af[i] = *(const bf16x8*)(smem + r * 512 + ((sc ^ (r & 7)) * 16));
    }
#pragma unroll
    for (int j = 0; j < 2; ++j) {
      int r = wid * 32 + j * 16 + (lane & 15);
      int slot = (lane >> 4) ^ ((r + (r >> 2)) & 3);
      bfr[j] = *(const bf16x8*)(bufc + r * 64 + slot * 16);
    }
#pragma unroll
    for (int i = 0; i < 4; ++i)
#pragma unroll
      for (int j = 0; j < 2; ++j)
        acc[i][j] = __builtin_amdgcn_mfma_f32_16x16x32_bf16(af[i], bfr[j],
                                                            acc[i][j], 0, 0, 0);
    __syncthreads();
  }

  const int rbase = (lane >> 4) * 4;
  const int cn = lane & 15;
#pragma unroll
  for (int i = 0; i < 4; ++i)
#pragma unroll
    for (int j = 0; j < 2; ++j) {
      int col = wid * 32 + j * 16 + cn;
      float bs = b_out[col];
#pragma unroll
      for (int r = 0; r < 4; ++r) {
        int row = i * 16 + rbase + r;
        out[(row0 + row) * DMODEL + col] = acc[i][j][r] + bs;
      }
    }
}

// ---------------------------------------------------------------------------
extern "C" void kernel_launch(void* const* d_in, const int* in_sizes, int n_in,
                              void* d_out, int out_size, void* d_ws,
                              size_t ws_size, hipStream_t stream) {
  const float* x       = (const float*)d_in[0];
  const float* A_log   = (const float*)d_in[1];
  const float* D_skip  = (const float*)d_in[2];
  const float* W_B     = (const float*)d_in[3];
  const float* W_C     = (const float*)d_in[4];
  const float* W_delta = (const float*)d_in[5];
  const float* b_delta = (const float*)d_in[6];
  const float* W_in    = (const float*)d_in[7];
  const float* b_in    = (const float*)d_in[8];
  const float* W_out   = (const float*)d_in[9];
  const float* b_out   = (const float*)d_in[10];
  const float* conv_w  = (const float*)d_in[11];
  const float* conv_b  = (const float*)d_in[12];

  const size_t MD = (size_t)MROWS * DMODEL;                // 16.78M
  const size_t HP = (size_t)BATCH * NCHB * DMODEL * NST;   // 4.19M
  ushort* xinb = (ushort*)d_ws;             // x_in bf16 [MD]
  ushort* dl   = xinb + MD;                 // delta fp16 [MD]
  ushort* szy  = dl + MD;                   // silu(z) bf16 [MD]
  ushort* xcb  = szy + MD;                  // xc bf16 [MD]
  ushort* bcb  = xcb + MD;                  // bc bf16 [MROWS*32]
  float* hst   = (float*)(bcb + (size_t)MROWS * 32);  // h_out -> h_in [HP]
  float* cumA  = hst + HP;                  // [HP]
  ushort* wbf  = (ushort*)(cumA + HP);      // bf16 weights, 270336

  cvt_weights<<<dim3(132), 256, 0, stream>>>(W_in, W_delta, W_out, W_B, W_C, wbf);
  gemm_in<<<dim3(2, MROWS / 64), 256, 0, stream>>>(x, wbf, b_in, xinb, szy);
  fused_mid<<<dim3(BATCH * NCHB), 512, 0, stream>>>(
      xinb, wbf + 131072, wbf + 262144, b_delta, A_log, conv_w, conv_b,
      xcb, dl, bcb, hst, cumA);
  scan_combine<<<dim3(BATCH * DMODEL * NST / 256), 256, 0, stream>>>(hst, cumA);
  fused_out<<<dim3(BATCH * NCHB), 512, 0, stream>>>(
      dl, xcb, szy, bcb, A_log, hst, D_skip, wbf + 196608, b_out,
      (float*)d_out);
}

// Round 13
// 197.342 us; speedup vs baseline: 1.2925x; 1.0072x over previous
//
#include <hip/hip_runtime.h>
#include <hip/hip_bf16.h>
#include <math.h>

#define BATCH 16
#define LSEQ 4096
#define DMODEL 256
#define NST 16
#define LC 64                   // rows per fused block / scan chunk
#define NCHB (LSEQ / LC)        // 64 chunks per batch
#define MROWS (BATCH * LSEQ)    // 65536
#define LOG2E 1.44269504088896340736f
#define LN2 0.6931471805599453f

typedef float f32x4 __attribute__((ext_vector_type(4)));
typedef float f32x2 __attribute__((ext_vector_type(2)));
typedef short bf16x8 __attribute__((ext_vector_type(8)));

__device__ __forceinline__ float silu_fast(float v) {
  return v * __builtin_amdgcn_rcpf(1.f + __builtin_amdgcn_exp2f(-v * LOG2E));
}
__device__ __forceinline__ float softplus_fast(float v) {
  float l = LN2 * __builtin_amdgcn_logf(1.f + __builtin_amdgcn_exp2f(v * LOG2E));
  return v > 16.f ? v : l;
}
__device__ __forceinline__ uint bf16rne(float f) {
  uint u = __float_as_uint(f);
  return (u + 0x7fffu + ((u >> 16) & 1u)) >> 16;
}
__device__ __forceinline__ float bf2f(ushort u) {
  return __uint_as_float((uint)u << 16);
}
__device__ __forceinline__ ushort f2h(float v) {
  _Float16 h = (_Float16)v;
  return __builtin_bit_cast(ushort, h);
}
__device__ __forceinline__ float h2f(ushort u) {
  return (float)__builtin_bit_cast(_Float16, u);
}
__device__ __forceinline__ uint pk2(float x, float y) {
  return bf16rne(x) | (bf16rne(y) << 16);
}
__device__ __forceinline__ uint4 pk8(float4 a, float4 b) {
  uint4 r;
  r.x = pk2(a.x, a.y);
  r.y = pk2(a.z, a.w);
  r.z = pk2(b.x, b.y);
  r.w = pk2(b.z, b.w);
  return r;
}
// unpack 8 bf16 (uint4) -> 8 floats
__device__ __forceinline__ void ub8(uint4 v, float* o) {
  o[0] = bf2f((ushort)(v.x & 0xffff));
  o[1] = bf2f((ushort)(v.x >> 16));
  o[2] = bf2f((ushort)(v.y & 0xffff));
  o[3] = bf2f((ushort)(v.y >> 16));
  o[4] = bf2f((ushort)(v.z & 0xffff));
  o[5] = bf2f((ushort)(v.z >> 16));
  o[6] = bf2f((ushort)(v.w & 0xffff));
  o[7] = bf2f((ushort)(v.w >> 16));
}

// packed powers: p01={e1,e2} p23={e3,e4} p45={e5,e6} p67={e7,e8}, then
// all scaled by (s ? e8 : 1). Same multiplication pairings as the scalar
// pow tree -> bit-identical products. ~1 mul + 3 pk_mul + 4 pk_mul(sel).
__device__ __forceinline__ void pow8pk(float e1, int s, f32x2* p) {
  float e2 = e1 * e1;
  p[0] = f32x2{e1, e2};
  f32x2 e2v = {e2, e2};
  p[1] = p[0] * e2v;                 // {e3, e4}
  f32x2 e4v = {p[1].y, p[1].y};
  p[2] = p[0] * e4v;                 // {e5, e6}
  p[3] = p[1] * e4v;                 // {e7, e8}
  float sel = s ? p[3].y : 1.0f;
  f32x2 selv = {sel, sel};
  p[0] *= selv;
  p[1] *= selv;
  p[2] *= selv;
  p[3] *= selv;
}

// async global(bf16)->LDS, 16 B per lane
__device__ __forceinline__ void glds16(const ushort* g, char* l) {
  __builtin_amdgcn_global_load_lds(
      (const __attribute__((address_space(1))) void*)g,
      (__attribute__((address_space(3))) void*)l, 16, 0, 0);
}

// stage a 256x32 bf16 B k-slice (swizzled layout r*64 + slot*16,
// slot = chunk ^ ((r+(r>>2))&3)); 512 thr: wave w covers 1KB blocks 2w,2w+1.
__device__ __forceinline__ void stageB512(const ushort* gbase, char* dst,
                                          int k0, int lane, int wid) {
#pragma unroll
  for (int c = 0; c < 2; ++c) {
    int r = (wid * 2 + c) * 16 + (lane >> 2);
    int sA = (r + (r >> 2)) & 3;
    int cA = (lane & 3) ^ sA;
    glds16(gbase + (size_t)r * 256 + cA * 8 + k0, dst + (wid * 2 + c) * 1024);
  }
}

// ---------------------------------------------------------------------------
// Weight fp32->bf16 convert (layout unchanged).
// ---------------------------------------------------------------------------
__global__ __launch_bounds__(256) void cvt_weights(
    const float* __restrict__ Win, const float* __restrict__ Wd,
    const float* __restrict__ Wo, const float* __restrict__ WB,
    const float* __restrict__ WC, ushort* __restrict__ dst) {
  size_t i = ((size_t)blockIdx.x * 256 + threadIdx.x) * 8;
  if (i >= 270336) return;
  const float* s;
  size_t o;
  if (i < 131072)      { s = Win; o = i; }
  else if (i < 196608) { s = Wd;  o = i - 131072; }
  else if (i < 262144) { s = Wo;  o = i - 196608; }
  else if (i < 266240) { s = WB;  o = i - 262144; }
  else                 { s = WC;  o = i - 266240; }
  float4 a = *(const float4*)(s + o);
  float4 b = *(const float4*)(s + o + 4);
  *(uint4*)(dst + i) = pk8(a, b);
}

// ---------------------------------------------------------------------------
// gemm_in: xz = x @ W_in^T + b_in. Tile 64x256, grid (2, M/64);
// col<256 -> x_in bf16, col>=256 -> silu(z) bf16.
// ---------------------------------------------------------------------------
__global__ __launch_bounds__(256, 4) void gemm_in(
    const float* __restrict__ A, const ushort* __restrict__ Bbf,
    const float* __restrict__ bias, ushort* __restrict__ out0,
    ushort* __restrict__ out1) {
  constexpr int KD = 256;
  __shared__ char smem[40960];
  const int tid = threadIdx.x;
  const int lane = tid & 63, wid = tid >> 6;
  const int M0 = blockIdx.y * 64;
  const int N0 = blockIdx.x * 256;

  const int rA = tid >> 2, cA = tid & 3;
  const int sA = (rA + (rA >> 2)) & 3;
  const int ldsAoff = rA * 64 + ((cA ^ sA) * 16);
  const float* gA32 = A + (size_t)(M0 + rA) * KD + cA * 8;
  const ushort* gB = Bbf + (size_t)(N0 + rA) * KD + ((cA ^ sA) * 8);

  f32x4 acc[4][4];
#pragma unroll
  for (int i = 0; i < 4; ++i)
#pragma unroll
    for (int j = 0; j < 4; ++j) acc[i][j] = {0.f, 0.f, 0.f, 0.f};

  {
#pragma unroll
    for (int i = 0; i < 4; ++i)
      glds16(gB + (size_t)i * 64 * KD, smem + 4096 + i * 4096 + wid * 1024);
    float4 a0 = *(const float4*)(gA32);
    float4 a1 = *(const float4*)(gA32 + 4);
    *(uint4*)(smem + ldsAoff) = pk8(a0, a1);
  }
  __syncthreads();

  for (int step = 0; step < 8; ++step) {
    const int cur = step & 1;
    char* bufc = smem + cur * 20480;
    char* bufn = smem + (cur ^ 1) * 20480;
    float4 na0, na1;
    if (step < 7) {
      const int k0 = (step + 1) * 32;
#pragma unroll
      for (int i = 0; i < 4; ++i)
        glds16(gB + (size_t)i * 64 * KD + k0,
               bufn + 4096 + i * 4096 + wid * 1024);
      na0 = *(const float4*)(gA32 + k0);
      na1 = *(const float4*)(gA32 + k0 + 4);
    }
    bf16x8 af[4], bfr[4];
#pragma unroll
    for (int i = 0; i < 4; ++i) {
      int r = i * 16 + (lane & 15);
      int slot = (lane >> 4) ^ ((r + (r >> 2)) & 3);
      af[i] = *(const bf16x8*)(bufc + r * 64 + slot * 16);
    }
#pragma unroll
    for (int j = 0; j < 4; ++j) {
      int r = wid * 64 + j * 16 + (lane & 15);
      int slot = (lane >> 4) ^ ((r + (r >> 2)) & 3);
      bfr[j] = *(const bf16x8*)(bufc + 4096 + r * 64 + slot * 16);
    }
#pragma unroll
    for (int i = 0; i < 4; ++i)
#pragma unroll
      for (int j = 0; j < 4; ++j)
        acc[i][j] = __builtin_amdgcn_mfma_f32_16x16x32_bf16(af[i], bfr[j],
                                                            acc[i][j], 0, 0, 0);
    if (step < 7) *(uint4*)(bufn + ldsAoff) = pk8(na0, na1);
    __syncthreads();
  }

  const int rbase = (lane >> 4) * 4;
  const int cn = lane & 15;
#pragma unroll
  for (int i = 0; i < 4; ++i) {
#pragma unroll
    for (int j = 0; j < 4; ++j) {
      int col = N0 + wid * 64 + j * 16 + cn;
      float bs = bias[col];
#pragma unroll
      for (int r = 0; r < 4; ++r) {
        int row = M0 + i * 16 + rbase + r;
        float v = acc[i][j][r] + bs;
        if (col < DMODEL)
          out0[(size_t)row * DMODEL + col] = (ushort)bf16rne(v);
        else
          out1[(size_t)row * DMODEL + (col - DMODEL)] =
              (ushort)bf16rne(silu_fast(v));
      }
    }
  }
}

// ---------------------------------------------------------------------------
// K2 fused_mid (512 thr, 72 KB LDS): conv+silu -> xc tile, delta GEMM
// (single-buffered W_delta), BC GEMM (interleaved), scan pass1 n-split
// with packed-f32 inner loop.
// ---------------------------------------------------------------------------
__global__ __launch_bounds__(512, 4) void fused_mid(
    const ushort* __restrict__ xin, const ushort* __restrict__ wdl,
    const ushort* __restrict__ wbc, const float* __restrict__ b_delta,
    const float* __restrict__ A_log, const float* __restrict__ conv_w,
    const float* __restrict__ conv_b, ushort* __restrict__ xc_g,
    ushort* __restrict__ dl_g, ushort* __restrict__ bc_g,
    float* __restrict__ hout, float* __restrict__ cumA) {
  __shared__ char smem[73728];
  const int tid = threadIdx.x, lane = tid & 63, wid = tid >> 6;
  const int b = blockIdx.x / NCHB, c = blockIdx.x % NCHB;
  const int l0 = c * LC;
  const size_t row0 = (size_t)b * LSEQ + l0;

  // ---- WBC staging -> @49152
  {
#pragma unroll
    for (int cc = 0; cc < 2; ++cc) {
      int row = (wid * 2 + cc) * 2 + (lane >> 5);
      int cB = (lane & 31) ^ (row & 7);
      glds16(wbc + (size_t)row * 256 + cB * 8,
             smem + 49152 + (wid * 2 + cc) * 1024);
    }
  }
  // ---- W_delta k-step 0 -> @32768
  stageB512(wdl, smem + 32768, 0, lane, wid);

  // ---- conv + silu -> xc tile + global (each thread 4 l-rows x 8 d)
  {
    const int dq = tid & 31;
    const int d0 = dq * 8;
    float w0[8], w1[8], w2[8], cb[8];
#pragma unroll
    for (int k = 0; k < 8; ++k) {
      w0[k] = conv_w[(d0 + k) * 3 + 0];
      w1[k] = conv_w[(d0 + k) * 3 + 1];
      w2[k] = conv_w[(d0 + k) * 3 + 2];
      cb[k] = conv_b[d0 + k];
    }
#pragma unroll
    for (int it = 0; it < 4; ++it) {
      const int lr = it * 16 + (tid >> 5);
      const int l = l0 + lr;
      const size_t bp = (row0 + lr) * DMODEL + d0;
      uint4 zf4 = {0u, 0u, 0u, 0u};
      uint4 um = (l > 0) ? *(const uint4*)(xin + bp - DMODEL) : zf4;
      uint4 uc4 = *(const uint4*)(xin + bp);
      uint4 up = (l < LSEQ - 1) ? *(const uint4*)(xin + bp + DMODEL) : zf4;
      float mv[8], cv[8], pv[8], ov[8];
      ub8(um, mv);
      ub8(uc4, cv);
      ub8(up, pv);
#pragma unroll
      for (int k = 0; k < 8; ++k) {
        float o = fmaf(w0[k], mv[k], fmaf(w1[k], cv[k], fmaf(w2[k], pv[k], cb[k])));
        ov[k] = silu_fast(o);
      }
      uint4 r4;
      r4.x = pk2(ov[0], ov[1]);
      r4.y = pk2(ov[2], ov[3]);
      r4.z = pk2(ov[4], ov[5]);
      r4.w = pk2(ov[6], ov[7]);
      *(uint4*)(xc_g + bp) = r4;
      *(uint4*)(smem + lr * 512 + ((dq ^ (lr & 7)) * 16)) = r4;
    }
  }
  __syncthreads();  // xc tile + WBC + B-k0 ready

  // ---- delta GEMM (single-buf B) with BC GEMM interleaved
  f32x4 acc[4][2];
#pragma unroll
  for (int i = 0; i < 4; ++i)
#pragma unroll
    for (int j = 0; j < 2; ++j) acc[i][j] = {0.f, 0.f, 0.f, 0.f};
  f32x4 accbc = {0.f, 0.f, 0.f, 0.f};

  for (int step = 0; step < 8; ++step) {
    bf16x8 af[4], bfr[2];
#pragma unroll
    for (int i = 0; i < 4; ++i) {
      int r = i * 16 + (lane & 15);
      int sc = step * 4 + (lane >> 4);
      af[i] = *(const bf16x8*)(smem + r * 512 + ((sc ^ (r & 7)) * 16));
    }
#pragma unroll
    for (int j = 0; j < 2; ++j) {
      int r = wid * 32 + j * 16 + (lane & 15);
      int slot = (lane >> 4) ^ ((r + (r >> 2)) & 3);
      bfr[j] = *(const bf16x8*)(smem + 32768 + r * 64 + slot * 16);
    }
#pragma unroll
    for (int i = 0; i < 4; ++i)
#pragma unroll
      for (int j = 0; j < 2; ++j)
        acc[i][j] = __builtin_amdgcn_mfma_f32_16x16x32_bf16(af[i], bfr[j],
                                                            acc[i][j], 0, 0, 0);
    __syncthreads();  // all reads of B buffer done
    if (step < 7) stageB512(wdl, smem + 32768, (step + 1) * 32, lane, wid);
    {  // BC GEMM step
      int sc = step * 4 + (lane >> 4);
      int ra = (wid >> 1) * 16 + (lane & 15);
      bf16x8 a2 = *(const bf16x8*)(smem + ra * 512 + ((sc ^ (ra & 7)) * 16));
      int br = (wid & 1) * 16 + (lane & 15);
      bf16x8 b2 =
          *(const bf16x8*)(smem + 49152 + br * 512 + ((sc ^ (br & 7)) * 16));
      accbc = __builtin_amdgcn_mfma_f32_16x16x32_bf16(a2, b2, accbc, 0, 0, 0);
    }
    __syncthreads();  // staged B visible
  }

  // ---- delta epilogue -> fp16 tile @32768, swz
  const int rbase = (lane >> 4) * 4;
  const int cn = lane & 15;
#pragma unroll
  for (int i = 0; i < 4; ++i)
#pragma unroll
    for (int j = 0; j < 2; ++j) {
      int col = wid * 32 + j * 16 + cn;
      float bs = b_delta[col];
#pragma unroll
      for (int r = 0; r < 4; ++r) {
        int row = i * 16 + rbase + r;
        *(ushort*)(smem + 32768 + row * 512 +
                   ((col * 2) ^ (((row >> 2) & 3) << 5))) =
            f2h(softplus_fast(acc[i][j][r] + bs));
      }
    }
  // ---- BC epilogue
  {
#pragma unroll
    for (int r = 0; r < 4; ++r) {
      int row = (wid >> 1) * 16 + rbase + r;
      int col = (wid & 1) * 16 + cn;
      ushort bv = (ushort)bf16rne(accbc[r]);
      ((float*)(smem + 65536))[row * 32 + col] = bf2f(bv);
      bc_g[(row0 + row) * 32 + col] = bv;
    }
  }
  __syncthreads();

  // ---- dl_g coalesced write
#pragma unroll
  for (int it = 0; it < 4; ++it) {
    int idx = it * 512 + tid;
    int row = idx >> 5, ch = idx & 31;
    *(uint4*)(dl_g + (row0 + row) * DMODEL + ch * 8) =
        *(const uint4*)(smem + 32768 + row * 512 +
                        ((ch ^ (((row >> 2) & 3) << 1)) * 16));
  }

  // ---- scan pass1, n-split, packed f32
  const int d = tid >> 1;
  const int s = tid & 1;
  float Aa2h[8];
  {
    float4 v0 = *(const float4*)(A_log + d * NST + 8 * s);
    float4 v1 = *(const float4*)(A_log + d * NST + 8 * s + 4);
    Aa2h[0] = -LOG2E * __expf(v0.x);
    Aa2h[1] = -LOG2E * __expf(v0.y);
    Aa2h[2] = -LOG2E * __expf(v0.z);
    Aa2h[3] = -LOG2E * __expf(v0.w);
    Aa2h[4] = -LOG2E * __expf(v1.x);
    Aa2h[5] = -LOG2E * __expf(v1.y);
    Aa2h[6] = -LOG2E * __expf(v1.z);
    Aa2h[7] = -LOG2E * __expf(v1.w);
  }
  const float Aa2_0 = -LOG2E * __expf(A_log[d * NST]);
  bool pm = true;
#pragma unroll
  for (int k = 0; k < 8; ++k)
    pm = pm && (fabsf(Aa2h[k] - (float)(8 * s + k + 1) * Aa2_0) <=
                1e-3f * fabsf(Aa2h[k]));

  float sdt = 0.f;
  const int uoff0 = (d & 7) * 2;
  const int uchunk = d >> 3;
  if (pm) {
    f32x2 h2[4];
#pragma unroll
    for (int q = 0; q < 4; ++q) h2[q] = f32x2{0.f, 0.f};
#pragma unroll 4
    for (int l = 0; l < LC; ++l) {
      float dt = h2f(*(const ushort*)(smem + 32768 + l * 512 +
                                      ((d * 2) ^ (((l >> 2) & 3) << 5))));
      float u = bf2f(*(const ushort*)(smem + l * 512 +
                                      ((uchunk ^ (l & 7)) * 16) + uoff0));
      sdt += dt;
      float dtu = dt * u;
      f32x2 dtu2 = {dtu, dtu};
      const float* Bp = (const float*)(smem + 65536) + l * 32 + 8 * s;
      f32x4 B0 = *(const f32x4*)(Bp);
      f32x4 B1 = *(const f32x4*)(Bp + 4);
      f32x2 p[4];
      pow8pk(__builtin_amdgcn_exp2f(dt * Aa2_0), s, p);
      h2[0] = p[0] * h2[0] + dtu2 * B0.xy;
      h2[1] = p[1] * h2[1] + dtu2 * B0.zw;
      h2[2] = p[2] * h2[2] + dtu2 * B1.xy;
      h2[3] = p[3] * h2[3] + dtu2 * B1.zw;
    }
    f32x2 cum[4];
    pow8pk(__builtin_amdgcn_exp2f(sdt * Aa2_0), s, cum);
    const size_t ob =
        (((size_t)(b * NCHB + c)) * DMODEL + d) * NST + 8 * s;
    float4 hv0 = {h2[0].x, h2[0].y, h2[1].x, h2[1].y};
    float4 hv1 = {h2[2].x, h2[2].y, h2[3].x, h2[3].y};
    *(float4*)(hout + ob) = hv0;
    *(float4*)(hout + ob + 4) = hv1;
    float4 cv0 = {cum[0].x, cum[0].y, cum[1].x, cum[1].y};
    float4 cv1 = {cum[2].x, cum[2].y, cum[3].x, cum[3].y};
    *(float4*)(cumA + ob) = cv0;
    *(float4*)(cumA + ob + 4) = cv1;
  } else {
    float h[8];
#pragma unroll
    for (int k = 0; k < 8; ++k) h[k] = 0.f;
#pragma unroll 4
    for (int l = 0; l < LC; ++l) {
      float dt = h2f(*(const ushort*)(smem + 32768 + l * 512 +
                                      ((d * 2) ^ (((l >> 2) & 3) << 5))));
      float u = bf2f(*(const ushort*)(smem + l * 512 +
                                      ((uchunk ^ (l & 7)) * 16) + uoff0));
      sdt += dt;
      float dtu = dt * u;
      const float* Bp = (const float*)(smem + 65536) + l * 32 + 8 * s;
      f32x4 B0 = *(const f32x4*)(Bp);
      f32x4 B1 = *(const f32x4*)(Bp + 4);
      float Bv[8] = {B0.x, B0.y, B0.z, B0.w, B1.x, B1.y, B1.z, B1.w};
#pragma unroll
      for (int k = 0; k < 8; ++k) {
        float ab = __builtin_amdgcn_exp2f(dt * Aa2h[k]);
        h[k] = fmaf(ab, h[k], dtu * Bv[k]);
      }
    }
    const size_t ob =
        (((size_t)(b * NCHB + c)) * DMODEL + d) * NST + 8 * s;
#pragma unroll
    for (int q = 0; q < 2; ++q) {
      float4 hv = {h[q * 4 + 0], h[q * 4 + 1], h[q * 4 + 2], h[q * 4 + 3]};
      *(float4*)(hout + ob + q * 4) = hv;
      float4 cvv = {__builtin_amdgcn_exp2f(sdt * Aa2h[q * 4 + 0]),
                    __builtin_amdgcn_exp2f(sdt * Aa2h[q * 4 + 1]),
                    __builtin_amdgcn_exp2f(sdt * Aa2h[q * 4 + 2]),
                    __builtin_amdgcn_exp2f(sdt * Aa2h[q * 4 + 3])};
      *(float4*)(cumA + ob + q * 4) = cvv;
    }
  }
}

// ---------------------------------------------------------------------------
// Scan combine over 64 chunks; in-place h_out -> h_in.
// ---------------------------------------------------------------------------
__global__ __launch_bounds__(256) void scan_combine(
    float* __restrict__ hstate, const float* __restrict__ cumA) {
  const int t = blockIdx.x * 256 + threadIdx.x;
  const int n = t & (NST - 1);
  const int dd = (t / NST) & (DMODEL - 1);
  const int b = t / (NST * DMODEL);
  float h = 0.f;
  for (int c = 0; c < NCHB; ++c) {
    size_t idx = (((size_t)(b * NCHB + c)) * DMODEL + dd) * NST + n;
    float ho = hstate[idx];
    float ca = cumA[idx];
    hstate[idx] = h;
    h = fmaf(ca, h, ho);
  }
}

// ---------------------------------------------------------------------------
// K3 fused_out (512 thr, 72 KB LDS): scan pass3 (n-split, packed f32;
// s=0 lane owns z + yp + LDS write) -> y_pre tile -> GEMM W_out -> d_out.
// ---------------------------------------------------------------------------
__global__ __launch_bounds__(512, 4) void fused_out(
    const ushort* __restrict__ dl, const ushort* __restrict__ xcb,
    const ushort* __restrict__ szy, const ushort* __restrict__ bcb,
    const float* __restrict__ A_log, const float* __restrict__ hin,
    const float* __restrict__ Dskip, const ushort* __restrict__ wout,
    const float* __restrict__ b_out, float* __restrict__ out) {
  __shared__ char smem[73728];
  const int tid = threadIdx.x, lane = tid & 63, wid = tid >> 6;
  const int b = blockIdx.x / NCHB, c = blockIdx.x % NCHB;
  const int l0 = c * LC;
  const size_t row0 = (size_t)b * LSEQ + l0;

  // stage BC f32 tile
  {
    int r = tid >> 3, q = tid & 7;
    uint2 v = *(const uint2*)(bcb + (row0 + r) * 32 + q * 4);
    float* dp = (float*)(smem + 65536) + r * 32 + q * 4;
    dp[0] = bf2f((ushort)(v.x & 0xffff));
    dp[1] = bf2f((ushort)(v.x >> 16));
    dp[2] = bf2f((ushort)(v.y & 0xffff));
    dp[3] = bf2f((ushort)(v.y >> 16));
  }
  // issue W_out k-step 0
  stageB512(wout, smem + 32768, 0, lane, wid);

  // ---- scan setup (n-split)
  const int d = tid >> 1;
  const int s = tid & 1;
  float Aa2h[8];
  {
    float4 v0 = *(const float4*)(A_log + d * NST + 8 * s);
    float4 v1 = *(const float4*)(A_log + d * NST + 8 * s + 4);
    Aa2h[0] = -LOG2E * __expf(v0.x);
    Aa2h[1] = -LOG2E * __expf(v0.y);
    Aa2h[2] = -LOG2E * __expf(v0.z);
    Aa2h[3] = -LOG2E * __expf(v0.w);
    Aa2h[4] = -LOG2E * __expf(v1.x);
    Aa2h[5] = -LOG2E * __expf(v1.y);
    Aa2h[6] = -LOG2E * __expf(v1.z);
    Aa2h[7] = -LOG2E * __expf(v1.w);
  }
  const float Aa2_0 = -LOG2E * __expf(A_log[d * NST]);
  bool pm = true;
#pragma unroll
  for (int k = 0; k < 8; ++k)
    pm = pm && (fabsf(Aa2h[k] - (float)(8 * s + k + 1) * Aa2_0) <=
                1e-3f * fabsf(Aa2h[k]));
  f32x2 h2[4];
  const size_t hb =
      (((size_t)(b * NCHB + c)) * DMODEL + d) * NST + 8 * s;
  {
    float4 v0 = *(const float4*)(hin + hb);
    float4 v1 = *(const float4*)(hin + hb + 4);
    h2[0] = f32x2{v0.x, v0.y};
    h2[1] = f32x2{v0.z, v0.w};
    h2[2] = f32x2{v1.x, v1.y};
    h2[3] = f32x2{v1.z, v1.w};
  }
  const float dsk = Dskip[d];
  __syncthreads();  // BC tile ready

  // ---- scan, y_pre -> LDS (s=0 lane finishes + writes)
  const size_t base = row0 * DMODEL + d;
  const int ywoff = (d & 7) * 2;
  const int ywchunk = d >> 3;
  ushort dtr[4], ur[4], zr[4];
#pragma unroll
  for (int j = 0; j < 4; ++j) {
    dtr[j] = dl[base + (size_t)j * DMODEL];
    ur[j] = xcb[base + (size_t)j * DMODEL];
    if (s == 0) zr[j] = szy[base + (size_t)j * DMODEL];
  }
  for (int lb = 0; lb < LC / 4; ++lb) {
    ushort dtn[4], un[4], zn[4];
    if (lb < LC / 4 - 1) {
      size_t nb = base + (size_t)(lb * 4 + 4) * DMODEL;
#pragma unroll
      for (int j = 0; j < 4; ++j) {
        dtn[j] = dl[nb + (size_t)j * DMODEL];
        un[j] = xcb[nb + (size_t)j * DMODEL];
        if (s == 0) zn[j] = szy[nb + (size_t)j * DMODEL];
      }
    }
#pragma unroll
    for (int j = 0; j < 4; ++j) {
      int l = lb * 4 + j;
      float dt = h2f(dtr[j]);
      float u = bf2f(ur[j]);
      float dtu = dt * u;
      f32x2 dtu2 = {dtu, dtu};
      const float* Bp = (const float*)(smem + 65536) + l * 32 + 8 * s;
      f32x4 B0 = *(const f32x4*)(Bp);
      f32x4 B1 = *(const f32x4*)(Bp + 4);
      f32x4 C0 = *(const f32x4*)(Bp + 16);
      f32x4 C1 = *(const f32x4*)(Bp + 20);
      float y;
      if (pm) {
        f32x2 p[4];
        pow8pk(__builtin_amdgcn_exp2f(dt * Aa2_0), s, p);
        f32x2 y2 = {0.f, 0.f};
        h2[0] = p[0] * h2[0] + dtu2 * B0.xy;
        y2 = y2 + h2[0] * C0.xy;
        h2[1] = p[1] * h2[1] + dtu2 * B0.zw;
        y2 = y2 + h2[1] * C0.zw;
        h2[2] = p[2] * h2[2] + dtu2 * B1.xy;
        y2 = y2 + h2[2] * C1.xy;
        h2[3] = p[3] * h2[3] + dtu2 * B1.zw;
        y2 = y2 + h2[3] * C1.zw;
        y = y2.x + y2.y;
      } else {
        float Bv[8] = {B0.x, B0.y, B0.z, B0.w, B1.x, B1.y, B1.z, B1.w};
        float Cv[8] = {C0.x, C0.y, C0.z, C0.w, C1.x, C1.y, C1.z, C1.w};
        float hs[8] = {h2[0].x, h2[0].y, h2[1].x, h2[1].y,
                       h2[2].x, h2[2].y, h2[3].x, h2[3].y};
        y = 0.f;
#pragma unroll
        for (int k = 0; k < 8; ++k) {
          float ab = __builtin_amdgcn_exp2f(dt * Aa2h[k]);
          hs[k] = fmaf(ab, hs[k], dtu * Bv[k]);
          y = fmaf(hs[k], Cv[k], y);
        }
        h2[0] = f32x2{hs[0], hs[1]};
        h2[1] = f32x2{hs[2], hs[3]};
        h2[2] = f32x2{hs[4], hs[5]};
        h2[3] = f32x2{hs[6], hs[7]};
      }
      y += __shfl_xor(y, 1);  // combine the two n-halves
      if (s == 0) {
        float yp = (y + u * dsk) * bf2f(zr[j]);
        *(ushort*)(smem + l * 512 + ((ywchunk ^ (l & 7)) * 16) + ywoff) =
            (ushort)bf16rne(yp);
      }
    }
#pragma unroll
    for (int j = 0; j < 4; ++j) {
      dtr[j] = dtn[j];
      ur[j] = un[j];
      if (s == 0) zr[j] = zn[j];
    }
  }
  __syncthreads();  // ypre tile complete

  // ---- output GEMM: wave w -> cols w*32; acc 4x2; dbuf B
  f32x4 acc[4][2];
#pragma unroll
  for (int i = 0; i < 4; ++i)
#pragma unroll
    for (int j = 0; j < 2; ++j) acc[i][j] = {0.f, 0.f, 0.f, 0.f};

  for (int step = 0; step < 8; ++step) {
    char* bufc = smem + 32768 + (step & 1) * 16384;
    if (step < 7)
      stageB512(wout, smem + 32768 + ((step + 1) & 1) * 16384,
                (step + 1) * 32, lane, wid);
    bf16x8 af[4], bfr[2];
#pragma unroll
    for (int i = 0; i < 4; ++i) {
      int r = i * 16 + (lane & 15);
      int sc = step * 4 + (lane >> 4);
      af[i] = *(const bf16x8*)(smem + r * 512 + ((sc ^ (r & 7)) * 16));
    }
#pragma unroll
    for (int j = 0; j < 2; ++j) {
      int r = wid * 32 + j * 16 + (lane & 15);
      int slot = (lane >> 4) ^ ((r + (r >> 2)) & 3);
      bfr[j] = *(const bf16x8*)(bufc + r * 64 + slot * 16);
    }
#pragma unroll
    for (int i = 0; i < 4; ++i)
#pragma unroll
      for (int j = 0; j < 2; ++j)
        acc[i][j] = __builtin_amdgcn_mfma_f32_16x16x32_bf16(af[i], bfr[j],
                                                            acc[i][j], 0, 0, 0);
    __syncthreads();
  }

  const int rbase = (lane >> 4) * 4;
  const int cn = lane & 15;
#pragma unroll
  for (int i = 0; i < 4; ++i)
#pragma unroll
    for (int j = 0; j < 2; ++j) {
      int col = wid * 32 + j * 16 + cn;
      float bs = b_out[col];
#pragma unroll
      for (int r = 0; r < 4; ++r) {
        int row = i * 16 + rbase + r;
        out[(row0 + row) * DMODEL + col] = acc[i][j][r] + bs;
      }
    }
}

// ---------------------------------------------------------------------------
extern "C" void kernel_launch(void* const* d_in, const int* in_sizes, int n_in,
                              void* d_out, int out_size, void* d_ws,
                              size_t ws_size, hipStream_t stream) {
  const float* x       = (const float*)d_in[0];
  const float* A_log   = (const float*)d_in[1];
  const float* D_skip  = (const float*)d_in[2];
  const float* W_B     = (const float*)d_in[3];
  const float* W_C     = (const float*)d_in[4];
  const float* W_delta = (const float*)d_in[5];
  const float* b_delta = (const float*)d_in[6];
  const float* W_in    = (const float*)d_in[7];
  const float* b_in    = (const float*)d_in[8];
  const float* W_out   = (const float*)d_in[9];
  const float* b_out   = (const float*)d_in[10];
  const float* conv_w  = (const float*)d_in[11];
  const float* conv_b  = (const float*)d_in[12];

  const size_t MD = (size_t)MROWS * DMODEL;                // 16.78M
  const size_t HP = (size_t)BATCH * NCHB * DMODEL * NST;   // 4.19M
  ushort* xinb = (ushort*)d_ws;             // x_in bf16 [MD]
  ushort* dl   = xinb + MD;                 // delta fp16 [MD]
  ushort* szy  = dl + MD;                   // silu(z) bf16 [MD]
  ushort* xcb  = szy + MD;                  // xc bf16 [MD]
  ushort* bcb  = xcb + MD;                  // bc bf16 [MROWS*32]
  float* hst   = (float*)(bcb + (size_t)MROWS * 32);  // h_out -> h_in [HP]
  float* cumA  = hst + HP;                  // [HP]
  ushort* wbf  = (ushort*)(cumA + HP);      // bf16 weights, 270336

  cvt_weights<<<dim3(132), 256, 0, stream>>>(W_in, W_delta, W_out, W_B, W_C, wbf);
  gemm_in<<<dim3(2, MROWS / 64), 256, 0, stream>>>(x, wbf, b_in, xinb, szy);
  fused_mid<<<dim3(BATCH * NCHB), 512, 0, stream>>>(
      xinb, wbf + 131072, wbf + 262144, b_delta, A_log, conv_w, conv_b,
      xcb, dl, bcb, hst, cumA);
  scan_combine<<<dim3(BATCH * DMODEL * NST / 256), 256, 0, stream>>>(hst, cumA);
  fused_out<<<dim3(BATCH * NCHB), 512, 0, stream>>>(
      dl, xcb, szy, bcb, A_log, hst, D_skip, wbf + 196608, b_out,
      (float*)d_out);
}

// Round 14
// 195.885 us; speedup vs baseline: 1.3021x; 1.0074x over previous
//
#include <hip/hip_runtime.h>
#include <hip/hip_bf16.h>
#include <math.h>

#define BATCH 16
#define LSEQ 4096
#define DMODEL 256
#define NST 16
#define LC 64                   // rows per fused block / scan chunk
#define NCHB (LSEQ / LC)        // 64 chunks per batch
#define MROWS (BATCH * LSEQ)    // 65536
#define LOG2E 1.44269504088896340736f
#define LN2 0.6931471805599453f

typedef float f32x4 __attribute__((ext_vector_type(4)));
typedef float f32x2 __attribute__((ext_vector_type(2)));
typedef short bf16x8 __attribute__((ext_vector_type(8)));

__device__ __forceinline__ float silu_fast(float v) {
  return v * __builtin_amdgcn_rcpf(1.f + __builtin_amdgcn_exp2f(-v * LOG2E));
}
__device__ __forceinline__ float softplus_fast(float v) {
  float l = LN2 * __builtin_amdgcn_logf(1.f + __builtin_amdgcn_exp2f(v * LOG2E));
  return v > 16.f ? v : l;
}
__device__ __forceinline__ uint bf16rne(float f) {
  uint u = __float_as_uint(f);
  return (u + 0x7fffu + ((u >> 16) & 1u)) >> 16;
}
__device__ __forceinline__ float bf2f(ushort u) {
  return __uint_as_float((uint)u << 16);
}
__device__ __forceinline__ ushort f2h(float v) {
  _Float16 h = (_Float16)v;
  return __builtin_bit_cast(ushort, h);
}
__device__ __forceinline__ float h2f(ushort u) {
  return (float)__builtin_bit_cast(_Float16, u);
}
__device__ __forceinline__ uint pk2(float x, float y) {
  return bf16rne(x) | (bf16rne(y) << 16);
}
__device__ __forceinline__ uint4 pk8(float4 a, float4 b) {
  uint4 r;
  r.x = pk2(a.x, a.y);
  r.y = pk2(a.z, a.w);
  r.z = pk2(b.x, b.y);
  r.w = pk2(b.z, b.w);
  return r;
}
// unpack 8 bf16 (uint4) -> 8 floats
__device__ __forceinline__ void ub8(uint4 v, float* o) {
  o[0] = bf2f((ushort)(v.x & 0xffff));
  o[1] = bf2f((ushort)(v.x >> 16));
  o[2] = bf2f((ushort)(v.y & 0xffff));
  o[3] = bf2f((ushort)(v.y >> 16));
  o[4] = bf2f((ushort)(v.z & 0xffff));
  o[5] = bf2f((ushort)(v.z >> 16));
  o[6] = bf2f((ushort)(v.w & 0xffff));
  o[7] = bf2f((ushort)(v.w >> 16));
}

// packed powers: p01={e1,e2} p23={e3,e4} p45={e5,e6} p67={e7,e8}, then
// all scaled by (s ? e8 : 1). Same multiplication pairings as the scalar
// pow tree -> bit-identical products.
__device__ __forceinline__ void pow8pk(float e1, int s, f32x2* p) {
  float e2 = e1 * e1;
  p[0] = f32x2{e1, e2};
  f32x2 e2v = {e2, e2};
  p[1] = p[0] * e2v;                 // {e3, e4}
  f32x2 e4v = {p[1].y, p[1].y};
  p[2] = p[0] * e4v;                 // {e5, e6}
  p[3] = p[1] * e4v;                 // {e7, e8}
  float sel = s ? p[3].y : 1.0f;
  f32x2 selv = {sel, sel};
  p[0] *= selv;
  p[1] *= selv;
  p[2] *= selv;
  p[3] *= selv;
}

// async global(bf16)->LDS, 16 B per lane
__device__ __forceinline__ void glds16(const ushort* g, char* l) {
  __builtin_amdgcn_global_load_lds(
      (const __attribute__((address_space(1))) void*)g,
      (__attribute__((address_space(3))) void*)l, 16, 0, 0);
}

// stage a 256x32 bf16 B k-slice (swizzled layout r*64 + slot*16,
// slot = chunk ^ ((r+(r>>2))&3)); 512 thr: wave w covers 1KB blocks 2w,2w+1.
__device__ __forceinline__ void stageB512(const ushort* gbase, char* dst,
                                          int k0, int lane, int wid) {
#pragma unroll
  for (int c = 0; c < 2; ++c) {
    int r = (wid * 2 + c) * 16 + (lane >> 2);
    int sA = (r + (r >> 2)) & 3;
    int cA = (lane & 3) ^ sA;
    glds16(gbase + (size_t)r * 256 + cA * 8 + k0, dst + (wid * 2 + c) * 1024);
  }
}

// ---------------------------------------------------------------------------
// Weight fp32->bf16 convert (layout unchanged).
// ---------------------------------------------------------------------------
__global__ __launch_bounds__(256) void cvt_weights(
    const float* __restrict__ Win, const float* __restrict__ Wd,
    const float* __restrict__ Wo, const float* __restrict__ WB,
    const float* __restrict__ WC, ushort* __restrict__ dst) {
  size_t i = ((size_t)blockIdx.x * 256 + threadIdx.x) * 8;
  if (i >= 270336) return;
  const float* s;
  size_t o;
  if (i < 131072)      { s = Win; o = i; }
  else if (i < 196608) { s = Wd;  o = i - 131072; }
  else if (i < 262144) { s = Wo;  o = i - 196608; }
  else if (i < 266240) { s = WB;  o = i - 262144; }
  else                 { s = WC;  o = i - 266240; }
  float4 a = *(const float4*)(s + o);
  float4 b = *(const float4*)(s + o + 4);
  *(uint4*)(dst + i) = pk8(a, b);
}

// ---------------------------------------------------------------------------
// gemm_in: xz = x @ W_in^T + b_in. Tile 64x256, grid (2, M/64);
// col<256 -> x_in bf16, col>=256 -> silu(z) bf16.
// ---------------------------------------------------------------------------
__global__ __launch_bounds__(256, 4) void gemm_in(
    const float* __restrict__ A, const ushort* __restrict__ Bbf,
    const float* __restrict__ bias, ushort* __restrict__ out0,
    ushort* __restrict__ out1) {
  constexpr int KD = 256;
  __shared__ char smem[40960];
  const int tid = threadIdx.x;
  const int lane = tid & 63, wid = tid >> 6;
  const int M0 = blockIdx.y * 64;
  const int N0 = blockIdx.x * 256;

  const int rA = tid >> 2, cA = tid & 3;
  const int sA = (rA + (rA >> 2)) & 3;
  const int ldsAoff = rA * 64 + ((cA ^ sA) * 16);
  const float* gA32 = A + (size_t)(M0 + rA) * KD + cA * 8;
  const ushort* gB = Bbf + (size_t)(N0 + rA) * KD + ((cA ^ sA) * 8);

  f32x4 acc[4][4];
#pragma unroll
  for (int i = 0; i < 4; ++i)
#pragma unroll
    for (int j = 0; j < 4; ++j) acc[i][j] = {0.f, 0.f, 0.f, 0.f};

  {
#pragma unroll
    for (int i = 0; i < 4; ++i)
      glds16(gB + (size_t)i * 64 * KD, smem + 4096 + i * 4096 + wid * 1024);
    float4 a0 = *(const float4*)(gA32);
    float4 a1 = *(const float4*)(gA32 + 4);
    *(uint4*)(smem + ldsAoff) = pk8(a0, a1);
  }
  __syncthreads();

  for (int step = 0; step < 8; ++step) {
    const int cur = step & 1;
    char* bufc = smem + cur * 20480;
    char* bufn = smem + (cur ^ 1) * 20480;
    float4 na0, na1;
    if (step < 7) {
      const int k0 = (step + 1) * 32;
#pragma unroll
      for (int i = 0; i < 4; ++i)
        glds16(gB + (size_t)i * 64 * KD + k0,
               bufn + 4096 + i * 4096 + wid * 1024);
      na0 = *(const float4*)(gA32 + k0);
      na1 = *(const float4*)(gA32 + k0 + 4);
    }
    bf16x8 af[4], bfr[4];
#pragma unroll
    for (int i = 0; i < 4; ++i) {
      int r = i * 16 + (lane & 15);
      int slot = (lane >> 4) ^ ((r + (r >> 2)) & 3);
      af[i] = *(const bf16x8*)(bufc + r * 64 + slot * 16);
    }
#pragma unroll
    for (int j = 0; j < 4; ++j) {
      int r = wid * 64 + j * 16 + (lane & 15);
      int slot = (lane >> 4) ^ ((r + (r >> 2)) & 3);
      bfr[j] = *(const bf16x8*)(bufc + 4096 + r * 64 + slot * 16);
    }
#pragma unroll
    for (int i = 0; i < 4; ++i)
#pragma unroll
      for (int j = 0; j < 4; ++j)
        acc[i][j] = __builtin_amdgcn_mfma_f32_16x16x32_bf16(af[i], bfr[j],
                                                            acc[i][j], 0, 0, 0);
    if (step < 7) *(uint4*)(bufn + ldsAoff) = pk8(na0, na1);
    __syncthreads();
  }

  const int rbase = (lane >> 4) * 4;
  const int cn = lane & 15;
#pragma unroll
  for (int i = 0; i < 4; ++i) {
#pragma unroll
    for (int j = 0; j < 4; ++j) {
      int col = N0 + wid * 64 + j * 16 + cn;
      float bs = bias[col];
#pragma unroll
      for (int r = 0; r < 4; ++r) {
        int row = M0 + i * 16 + rbase + r;
        float v = acc[i][j][r] + bs;
        if (col < DMODEL)
          out0[(size_t)row * DMODEL + col] = (ushort)bf16rne(v);
        else
          out1[(size_t)row * DMODEL + (col - DMODEL)] =
              (ushort)bf16rne(silu_fast(v));
      }
    }
  }
}

// ---------------------------------------------------------------------------
// K2 fused_mid (512 thr, 72 KB LDS): conv+silu -> xc tile, delta GEMM
// (single-buffered W_delta), BC GEMM (interleaved), scan pass1 n-split
// with packed-f32 inner loop.
// ---------------------------------------------------------------------------
__global__ __launch_bounds__(512, 4) void fused_mid(
    const ushort* __restrict__ xin, const ushort* __restrict__ wdl,
    const ushort* __restrict__ wbc, const float* __restrict__ b_delta,
    const float* __restrict__ A_log, const float* __restrict__ conv_w,
    const float* __restrict__ conv_b, ushort* __restrict__ xc_g,
    ushort* __restrict__ dl_g, ushort* __restrict__ bc_g,
    float* __restrict__ hout, float* __restrict__ cumA) {
  __shared__ char smem[73728];
  const int tid = threadIdx.x, lane = tid & 63, wid = tid >> 6;
  const int b = blockIdx.x / NCHB, c = blockIdx.x % NCHB;
  const int l0 = c * LC;
  const size_t row0 = (size_t)b * LSEQ + l0;

  // ---- WBC staging -> @49152
  {
#pragma unroll
    for (int cc = 0; cc < 2; ++cc) {
      int row = (wid * 2 + cc) * 2 + (lane >> 5);
      int cB = (lane & 31) ^ (row & 7);
      glds16(wbc + (size_t)row * 256 + cB * 8,
             smem + 49152 + (wid * 2 + cc) * 1024);
    }
  }
  // ---- W_delta k-step 0 -> @32768
  stageB512(wdl, smem + 32768, 0, lane, wid);

  // ---- conv + silu -> xc tile + global (each thread 4 l-rows x 8 d)
  {
    const int dq = tid & 31;
    const int d0 = dq * 8;
    float w0[8], w1[8], w2[8], cb[8];
#pragma unroll
    for (int k = 0; k < 8; ++k) {
      w0[k] = conv_w[(d0 + k) * 3 + 0];
      w1[k] = conv_w[(d0 + k) * 3 + 1];
      w2[k] = conv_w[(d0 + k) * 3 + 2];
      cb[k] = conv_b[d0 + k];
    }
#pragma unroll
    for (int it = 0; it < 4; ++it) {
      const int lr = it * 16 + (tid >> 5);
      const int l = l0 + lr;
      const size_t bp = (row0 + lr) * DMODEL + d0;
      uint4 zf4 = {0u, 0u, 0u, 0u};
      uint4 um = (l > 0) ? *(const uint4*)(xin + bp - DMODEL) : zf4;
      uint4 uc4 = *(const uint4*)(xin + bp);
      uint4 up = (l < LSEQ - 1) ? *(const uint4*)(xin + bp + DMODEL) : zf4;
      float mv[8], cv[8], pv[8], ov[8];
      ub8(um, mv);
      ub8(uc4, cv);
      ub8(up, pv);
#pragma unroll
      for (int k = 0; k < 8; ++k) {
        float o = fmaf(w0[k], mv[k], fmaf(w1[k], cv[k], fmaf(w2[k], pv[k], cb[k])));
        ov[k] = silu_fast(o);
      }
      uint4 r4;
      r4.x = pk2(ov[0], ov[1]);
      r4.y = pk2(ov[2], ov[3]);
      r4.z = pk2(ov[4], ov[5]);
      r4.w = pk2(ov[6], ov[7]);
      *(uint4*)(xc_g + bp) = r4;
      *(uint4*)(smem + lr * 512 + ((dq ^ (lr & 7)) * 16)) = r4;
    }
  }
  __syncthreads();  // xc tile + WBC + B-k0 ready

  // ---- delta GEMM (single-buf B) with BC GEMM interleaved
  f32x4 acc[4][2];
#pragma unroll
  for (int i = 0; i < 4; ++i)
#pragma unroll
    for (int j = 0; j < 2; ++j) acc[i][j] = {0.f, 0.f, 0.f, 0.f};
  f32x4 accbc = {0.f, 0.f, 0.f, 0.f};

  for (int step = 0; step < 8; ++step) {
    bf16x8 af[4], bfr[2];
#pragma unroll
    for (int i = 0; i < 4; ++i) {
      int r = i * 16 + (lane & 15);
      int sc = step * 4 + (lane >> 4);
      af[i] = *(const bf16x8*)(smem + r * 512 + ((sc ^ (r & 7)) * 16));
    }
#pragma unroll
    for (int j = 0; j < 2; ++j) {
      int r = wid * 32 + j * 16 + (lane & 15);
      int slot = (lane >> 4) ^ ((r + (r >> 2)) & 3);
      bfr[j] = *(const bf16x8*)(smem + 32768 + r * 64 + slot * 16);
    }
#pragma unroll
    for (int i = 0; i < 4; ++i)
#pragma unroll
      for (int j = 0; j < 2; ++j)
        acc[i][j] = __builtin_amdgcn_mfma_f32_16x16x32_bf16(af[i], bfr[j],
                                                            acc[i][j], 0, 0, 0);
    __syncthreads();  // all reads of B buffer done
    if (step < 7) stageB512(wdl, smem + 32768, (step + 1) * 32, lane, wid);
    {  // BC GEMM step
      int sc = step * 4 + (lane >> 4);
      int ra = (wid >> 1) * 16 + (lane & 15);
      bf16x8 a2 = *(const bf16x8*)(smem + ra * 512 + ((sc ^ (ra & 7)) * 16));
      int br = (wid & 1) * 16 + (lane & 15);
      bf16x8 b2 =
          *(const bf16x8*)(smem + 49152 + br * 512 + ((sc ^ (br & 7)) * 16));
      accbc = __builtin_amdgcn_mfma_f32_16x16x32_bf16(a2, b2, accbc, 0, 0, 0);
    }
    __syncthreads();  // staged B visible
  }

  // ---- delta epilogue -> fp16 tile @32768, swz
  const int rbase = (lane >> 4) * 4;
  const int cn = lane & 15;
#pragma unroll
  for (int i = 0; i < 4; ++i)
#pragma unroll
    for (int j = 0; j < 2; ++j) {
      int col = wid * 32 + j * 16 + cn;
      float bs = b_delta[col];
#pragma unroll
      for (int r = 0; r < 4; ++r) {
        int row = i * 16 + rbase + r;
        *(ushort*)(smem + 32768 + row * 512 +
                   ((col * 2) ^ (((row >> 2) & 3) << 5))) =
            f2h(softplus_fast(acc[i][j][r] + bs));
      }
    }
  // ---- BC epilogue
  {
#pragma unroll
    for (int r = 0; r < 4; ++r) {
      int row = (wid >> 1) * 16 + rbase + r;
      int col = (wid & 1) * 16 + cn;
      ushort bv = (ushort)bf16rne(accbc[r]);
      ((float*)(smem + 65536))[row * 32 + col] = bf2f(bv);
      bc_g[(row0 + row) * 32 + col] = bv;
    }
  }
  __syncthreads();

  // ---- dl_g coalesced write
#pragma unroll
  for (int it = 0; it < 4; ++it) {
    int idx = it * 512 + tid;
    int row = idx >> 5, ch = idx & 31;
    *(uint4*)(dl_g + (row0 + row) * DMODEL + ch * 8) =
        *(const uint4*)(smem + 32768 + row * 512 +
                        ((ch ^ (((row >> 2) & 3) << 1)) * 16));
  }

  // ---- scan pass1, n-split, packed f32
  const int d = tid >> 1;
  const int s = tid & 1;
  float Aa2h[8];
  {
    float4 v0 = *(const float4*)(A_log + d * NST + 8 * s);
    float4 v1 = *(const float4*)(A_log + d * NST + 8 * s + 4);
    Aa2h[0] = -LOG2E * __expf(v0.x);
    Aa2h[1] = -LOG2E * __expf(v0.y);
    Aa2h[2] = -LOG2E * __expf(v0.z);
    Aa2h[3] = -LOG2E * __expf(v0.w);
    Aa2h[4] = -LOG2E * __expf(v1.x);
    Aa2h[5] = -LOG2E * __expf(v1.y);
    Aa2h[6] = -LOG2E * __expf(v1.z);
    Aa2h[7] = -LOG2E * __expf(v1.w);
  }
  const float Aa2_0 = -LOG2E * __expf(A_log[d * NST]);
  bool pm = true;
#pragma unroll
  for (int k = 0; k < 8; ++k)
    pm = pm && (fabsf(Aa2h[k] - (float)(8 * s + k + 1) * Aa2_0) <=
                1e-3f * fabsf(Aa2h[k]));

  float sdt = 0.f;
  const int uoff0 = (d & 7) * 2;
  const int uchunk = d >> 3;
  if (pm) {
    f32x2 h2[4];
#pragma unroll
    for (int q = 0; q < 4; ++q) h2[q] = f32x2{0.f, 0.f};
#pragma unroll 4
    for (int l = 0; l < LC; ++l) {
      float dt = h2f(*(const ushort*)(smem + 32768 + l * 512 +
                                      ((d * 2) ^ (((l >> 2) & 3) << 5))));
      float u = bf2f(*(const ushort*)(smem + l * 512 +
                                      ((uchunk ^ (l & 7)) * 16) + uoff0));
      sdt += dt;
      float dtu = dt * u;
      f32x2 dtu2 = {dtu, dtu};
      const float* Bp = (const float*)(smem + 65536) + l * 32 + 8 * s;
      f32x4 B0 = *(const f32x4*)(Bp);
      f32x4 B1 = *(const f32x4*)(Bp + 4);
      f32x2 p[4];
      pow8pk(__builtin_amdgcn_exp2f(dt * Aa2_0), s, p);
      h2[0] = p[0] * h2[0] + dtu2 * B0.xy;
      h2[1] = p[1] * h2[1] + dtu2 * B0.zw;
      h2[2] = p[2] * h2[2] + dtu2 * B1.xy;
      h2[3] = p[3] * h2[3] + dtu2 * B1.zw;
    }
    f32x2 cum[4];
    pow8pk(__builtin_amdgcn_exp2f(sdt * Aa2_0), s, cum);
    const size_t ob =
        (((size_t)(b * NCHB + c)) * DMODEL + d) * NST + 8 * s;
    float4 hv0 = {h2[0].x, h2[0].y, h2[1].x, h2[1].y};
    float4 hv1 = {h2[2].x, h2[2].y, h2[3].x, h2[3].y};
    *(float4*)(hout + ob) = hv0;
    *(float4*)(hout + ob + 4) = hv1;
    float4 cv0 = {cum[0].x, cum[0].y, cum[1].x, cum[1].y};
    float4 cv1 = {cum[2].x, cum[2].y, cum[3].x, cum[3].y};
    *(float4*)(cumA + ob) = cv0;
    *(float4*)(cumA + ob + 4) = cv1;
  } else {
    float h[8];
#pragma unroll
    for (int k = 0; k < 8; ++k) h[k] = 0.f;
#pragma unroll 4
    for (int l = 0; l < LC; ++l) {
      float dt = h2f(*(const ushort*)(smem + 32768 + l * 512 +
                                      ((d * 2) ^ (((l >> 2) & 3) << 5))));
      float u = bf2f(*(const ushort*)(smem + l * 512 +
                                      ((uchunk ^ (l & 7)) * 16) + uoff0));
      sdt += dt;
      float dtu = dt * u;
      const float* Bp = (const float*)(smem + 65536) + l * 32 + 8 * s;
      f32x4 B0 = *(const f32x4*)(Bp);
      f32x4 B1 = *(const f32x4*)(Bp + 4);
      float Bv[8] = {B0.x, B0.y, B0.z, B0.w, B1.x, B1.y, B1.z, B1.w};
#pragma unroll
      for (int k = 0; k < 8; ++k) {
        float ab = __builtin_amdgcn_exp2f(dt * Aa2h[k]);
        h[k] = fmaf(ab, h[k], dtu * Bv[k]);
      }
    }
    const size_t ob =
        (((size_t)(b * NCHB + c)) * DMODEL + d) * NST + 8 * s;
#pragma unroll
    for (int q = 0; q < 2; ++q) {
      float4 hv = {h[q * 4 + 0], h[q * 4 + 1], h[q * 4 + 2], h[q * 4 + 3]};
      *(float4*)(hout + ob + q * 4) = hv;
      float4 cvv = {__builtin_amdgcn_exp2f(sdt * Aa2h[q * 4 + 0]),
                    __builtin_amdgcn_exp2f(sdt * Aa2h[q * 4 + 1]),
                    __builtin_amdgcn_exp2f(sdt * Aa2h[q * 4 + 2]),
                    __builtin_amdgcn_exp2f(sdt * Aa2h[q * 4 + 3])};
      *(float4*)(cumA + ob + q * 4) = cvv;
    }
  }
}

// ---------------------------------------------------------------------------
// Scan combine over 64 chunks; in-place h_out -> h_in.
// ---------------------------------------------------------------------------
__global__ __launch_bounds__(256) void scan_combine(
    float* __restrict__ hstate, const float* __restrict__ cumA) {
  const int t = blockIdx.x * 256 + threadIdx.x;
  const int n = t & (NST - 1);
  const int dd = (t / NST) & (DMODEL - 1);
  const int b = t / (NST * DMODEL);
  float h = 0.f;
  for (int c = 0; c < NCHB; ++c) {
    size_t idx = (((size_t)(b * NCHB + c)) * DMODEL + dd) * NST + n;
    float ho = hstate[idx];
    float ca = cumA[idx];
    hstate[idx] = h;
    h = fmaf(ca, h, ho);
  }
}

// ---------------------------------------------------------------------------
// K3 fused_out (512 thr, 72 KB LDS): scan pass3 (n-split, packed f32,
// 4-slot register pipeline with 3 batches in flight; s=0 lane owns z +
// yp + LDS write) -> y_pre tile -> GEMM W_out -> d_out.
// ---------------------------------------------------------------------------
__global__ __launch_bounds__(512, 4) void fused_out(
    const ushort* __restrict__ dl, const ushort* __restrict__ xcb,
    const ushort* __restrict__ szy, const ushort* __restrict__ bcb,
    const float* __restrict__ A_log, const float* __restrict__ hin,
    const float* __restrict__ Dskip, const ushort* __restrict__ wout,
    const float* __restrict__ b_out, float* __restrict__ out) {
  __shared__ char smem[73728];
  const int tid = threadIdx.x, lane = tid & 63, wid = tid >> 6;
  const int b = blockIdx.x / NCHB, c = blockIdx.x % NCHB;
  const int l0 = c * LC;
  const size_t row0 = (size_t)b * LSEQ + l0;

  // stage BC f32 tile
  {
    int r = tid >> 3, q = tid & 7;
    uint2 v = *(const uint2*)(bcb + (row0 + r) * 32 + q * 4);
    float* dp = (float*)(smem + 65536) + r * 32 + q * 4;
    dp[0] = bf2f((ushort)(v.x & 0xffff));
    dp[1] = bf2f((ushort)(v.x >> 16));
    dp[2] = bf2f((ushort)(v.y & 0xffff));
    dp[3] = bf2f((ushort)(v.y >> 16));
  }
  // issue W_out k-step 0
  stageB512(wout, smem + 32768, 0, lane, wid);

  // ---- scan setup (n-split)
  const int d = tid >> 1;
  const int s = tid & 1;
  float Aa2h[8];
  {
    float4 v0 = *(const float4*)(A_log + d * NST + 8 * s);
    float4 v1 = *(const float4*)(A_log + d * NST + 8 * s + 4);
    Aa2h[0] = -LOG2E * __expf(v0.x);
    Aa2h[1] = -LOG2E * __expf(v0.y);
    Aa2h[2] = -LOG2E * __expf(v0.z);
    Aa2h[3] = -LOG2E * __expf(v0.w);
    Aa2h[4] = -LOG2E * __expf(v1.x);
    Aa2h[5] = -LOG2E * __expf(v1.y);
    Aa2h[6] = -LOG2E * __expf(v1.z);
    Aa2h[7] = -LOG2E * __expf(v1.w);
  }
  const float Aa2_0 = -LOG2E * __expf(A_log[d * NST]);
  bool pm = true;
#pragma unroll
  for (int k = 0; k < 8; ++k)
    pm = pm && (fabsf(Aa2h[k] - (float)(8 * s + k + 1) * Aa2_0) <=
                1e-3f * fabsf(Aa2h[k]));
  f32x2 h2[4];
  const size_t hb =
      (((size_t)(b * NCHB + c)) * DMODEL + d) * NST + 8 * s;
  {
    float4 v0 = *(const float4*)(hin + hb);
    float4 v1 = *(const float4*)(hin + hb + 4);
    h2[0] = f32x2{v0.x, v0.y};
    h2[1] = f32x2{v0.z, v0.w};
    h2[2] = f32x2{v1.x, v1.y};
    h2[3] = f32x2{v1.z, v1.w};
  }
  const float dsk = Dskip[d];
  __syncthreads();  // BC tile ready

  // ---- scan, y_pre -> LDS. 4-slot register pipeline, 3 batches in flight.
  const size_t base = row0 * DMODEL + d;
  const int ywoff = (d & 7) * 2;
  const int ywchunk = d >> 3;
  ushort dta[4][4], ua[4][4], za[4][4];
#pragma unroll
  for (int q = 0; q < 3; ++q)
#pragma unroll
    for (int j = 0; j < 4; ++j) {
      size_t a = base + (size_t)(q * 4 + j) * DMODEL;
      dta[q][j] = dl[a];
      ua[q][j] = xcb[a];
      if (s == 0) za[q][j] = szy[a];
    }
#pragma unroll
  for (int lb = 0; lb < LC / 4; ++lb) {
    // prefetch batch lb+3 into the slot 3 ahead (distinct from current)
    if (lb + 3 < LC / 4) {
      const int ps = (lb + 3) & 3;
#pragma unroll
      for (int j = 0; j < 4; ++j) {
        size_t a = base + (size_t)((lb + 3) * 4 + j) * DMODEL;
        dta[ps][j] = dl[a];
        ua[ps][j] = xcb[a];
        if (s == 0) za[ps][j] = szy[a];
      }
    }
    const int cs = lb & 3;
#pragma unroll
    for (int j = 0; j < 4; ++j) {
      int l = lb * 4 + j;
      float dt = h2f(dta[cs][j]);
      float u = bf2f(ua[cs][j]);
      float dtu = dt * u;
      f32x2 dtu2 = {dtu, dtu};
      const float* Bp = (const float*)(smem + 65536) + l * 32 + 8 * s;
      f32x4 B0 = *(const f32x4*)(Bp);
      f32x4 B1 = *(const f32x4*)(Bp + 4);
      f32x4 C0 = *(const f32x4*)(Bp + 16);
      f32x4 C1 = *(const f32x4*)(Bp + 20);
      float y;
      if (pm) {
        f32x2 p[4];
        pow8pk(__builtin_amdgcn_exp2f(dt * Aa2_0), s, p);
        f32x2 y2 = {0.f, 0.f};
        h2[0] = p[0] * h2[0] + dtu2 * B0.xy;
        y2 = y2 + h2[0] * C0.xy;
        h2[1] = p[1] * h2[1] + dtu2 * B0.zw;
        y2 = y2 + h2[1] * C0.zw;
        h2[2] = p[2] * h2[2] + dtu2 * B1.xy;
        y2 = y2 + h2[2] * C1.xy;
        h2[3] = p[3] * h2[3] + dtu2 * B1.zw;
        y2 = y2 + h2[3] * C1.zw;
        y = y2.x + y2.y;
      } else {
        float Bv[8] = {B0.x, B0.y, B0.z, B0.w, B1.x, B1.y, B1.z, B1.w};
        float Cv[8] = {C0.x, C0.y, C0.z, C0.w, C1.x, C1.y, C1.z, C1.w};
        float hs[8] = {h2[0].x, h2[0].y, h2[1].x, h2[1].y,
                       h2[2].x, h2[2].y, h2[3].x, h2[3].y};
        y = 0.f;
#pragma unroll
        for (int k = 0; k < 8; ++k) {
          float ab = __builtin_amdgcn_exp2f(dt * Aa2h[k]);
          hs[k] = fmaf(ab, hs[k], dtu * Bv[k]);
          y = fmaf(hs[k], Cv[k], y);
        }
        h2[0] = f32x2{hs[0], hs[1]};
        h2[1] = f32x2{hs[2], hs[3]};
        h2[2] = f32x2{hs[4], hs[5]};
        h2[3] = f32x2{hs[6], hs[7]};
      }
      y += __shfl_xor(y, 1);  // combine the two n-halves
      if (s == 0) {
        float yp = (y + u * dsk) * bf2f(za[cs][j]);
        *(ushort*)(smem + l * 512 + ((ywchunk ^ (l & 7)) * 16) + ywoff) =
            (ushort)bf16rne(yp);
      }
    }
  }
  __syncthreads();  // ypre tile complete

  // ---- output GEMM: wave w -> cols w*32; acc 4x2; dbuf B
  f32x4 acc[4][2];
#pragma unroll
  for (int i = 0; i < 4; ++i)
#pragma unroll
    for (int j = 0; j < 2; ++j) acc[i][j] = {0.f, 0.f, 0.f, 0.f};

  for (int step = 0; step < 8; ++step) {
    char* bufc = smem + 32768 + (step & 1) * 16384;
    if (step < 7)
      stageB512(wout, smem + 32768 + ((step + 1) & 1) * 16384,
                (step + 1) * 32, lane, wid);
    bf16x8 af[4], bfr[2];
#pragma unroll
    for (int i = 0; i < 4; ++i) {
      int r = i * 16 + (lane & 15);
      int sc = step * 4 + (lane >> 4);
      af[i] = *(const bf16x8*)(smem + r * 512 + ((sc ^ (r & 7)) * 16));
    }
#pragma unroll
    for (int j = 0; j < 2; ++j) {
      int r = wid * 32 + j * 16 + (lane & 15);
      int slot = (lane >> 4) ^ ((r + (r >> 2)) & 3);
      bfr[j] = *(const bf16x8*)(bufc + r * 64 + slot * 16);
    }
#pragma unroll
    for (int i = 0; i < 4; ++i)
#pragma unroll
      for (int j = 0; j < 2; ++j)
        acc[i][j] = __builtin_amdgcn_mfma_f32_16x16x32_bf16(af[i], bfr[j],
                                                            acc[i][j], 0, 0, 0);
    __syncthreads();
  }

  const int rbase = (lane >> 4) * 4;
  const int cn = lane & 15;
#pragma unroll
  for (int i = 0; i < 4; ++i)
#pragma unroll
    for (int j = 0; j < 2; ++j) {
      int col = wid * 32 + j * 16 + cn;
      float bs = b_out[col];
#pragma unroll
      for (int r = 0; r < 4; ++r) {
        int row = i * 16 + rbase + r;
        out[(row0 + row) * DMODEL + col] = acc[i][j][r] + bs;
      }
    }
}

// ---------------------------------------------------------------------------
extern "C" void kernel_launch(void* const* d_in, const int* in_sizes, int n_in,
                              void* d_out, int out_size, void* d_ws,
                              size_t ws_size, hipStream_t stream) {
  const float* x       = (const float*)d_in[0];
  const float* A_log   = (const float*)d_in[1];
  const float* D_skip  = (const float*)d_in[2];
  const float* W_B     = (const float*)d_in[3];
  const float* W_C     = (const float*)d_in[4];
  const float* W_delta = (const float*)d_in[5];
  const float* b_delta = (const float*)d_in[6];
  const float* W_in    = (const float*)d_in[7];
  const float* b_in    = (const float*)d_in[8];
  const float* W_out   = (const float*)d_in[9];
  const float* b_out   = (const float*)d_in[10];
  const float* conv_w  = (const float*)d_in[11];
  const float* conv_b  = (const float*)d_in[12];

  const size_t MD = (size_t)MROWS * DMODEL;                // 16.78M
  const size_t HP = (size_t)BATCH * NCHB * DMODEL * NST;   // 4.19M
  ushort* xinb = (ushort*)d_ws;             // x_in bf16 [MD]
  ushort* dl   = xinb + MD;                 // delta fp16 [MD]
  ushort* szy  = dl + MD;                   // silu(z) bf16 [MD]
  ushort* xcb  = szy + MD;                  // xc bf16 [MD]
  ushort* bcb  = xcb + MD;                  // bc bf16 [MROWS*32]
  float* hst   = (float*)(bcb + (size_t)MROWS * 32);  // h_out -> h_in [HP]
  float* cumA  = hst + HP;                  // [HP]
  ushort* wbf  = (ushort*)(cumA + HP);      // bf16 weights, 270336

  cvt_weights<<<dim3(132), 256, 0, stream>>>(W_in, W_delta, W_out, W_B, W_C, wbf);
  gemm_in<<<dim3(2, MROWS / 64), 256, 0, stream>>>(x, wbf, b_in, xinb, szy);
  fused_mid<<<dim3(BATCH * NCHB), 512, 0, stream>>>(
      xinb, wbf + 131072, wbf + 262144, b_delta, A_log, conv_w, conv_b,
      xcb, dl, bcb, hst, cumA);
  scan_combine<<<dim3(BATCH * DMODEL * NST / 256), 256, 0, stream>>>(hst, cumA);
  fused_out<<<dim3(BATCH * NCHB), 512, 0, stream>>>(
      dl, xcb, szy, bcb, A_log, hst, D_skip, wbf + 196608, b_out,
      (float*)d_out);
}